// Round 1
// baseline (807.196 us; speedup 1.0000x reference)
//
#include <hip/hip_runtime.h>
#include <math.h>

#define TQ_  9

typedef unsigned int   u32;
typedef unsigned short ushort_t;
typedef short bf16x8 __attribute__((ext_vector_type(8)));
typedef float f32x4  __attribute__((ext_vector_type(4)));

#define WAIT_VMCNT0 0x0F70   // vmcnt(0)

__device__ __forceinline__ float bs2f(ushort_t s) {
  return __uint_as_float(((u32)s) << 16);
}
__device__ __forceinline__ ushort_t f2bs(float x) {   // round-to-nearest-even
  u32 u = __float_as_uint(x);
  u32 r = (u + 0x7FFFu + ((u >> 16) & 1u)) >> 16;
  return (ushort_t)r;
}
__device__ __forceinline__ void gload16(const void* g, void* l) {
  __builtin_amdgcn_global_load_lds((const __attribute__((address_space(1))) u32*)g,
                                   (__attribute__((address_space(3))) u32*)l, 16, 0, 0);
}

// ---------------------------------------------------------------------------
// Weight PACK: W f32 [K][N] -> MFMA-B-frag-linear bf16.
// Frag group G = (j*(K/32) + kk)*64 + q*16 + ln  holds 8 bf16:
//   element e: n = j*16+ln, k = kk*32 + q*8 + e.
// So lane (q*16+ln) of a wave reading 16B at G-linear offset gets exactly its
// mfma_f32_16x16x32_bf16 B-fragment — LDS reads are lane-linear (0 conflicts)
// and the HBM->LDS stage is a straight linear copy (global_load_lds-able).
// grid (32,32,10) guarded; z selects weight.
// ---------------------------------------------------------------------------
struct TPA { const float* s[10]; ushort_t* d[10]; int K[10]; int N[10]; };

__global__ __launch_bounds__(256)
void pack_all_kernel(TPA p) {
  int z = blockIdx.z;
  int K = p.K[z], N = p.N[z];
  int bn = blockIdx.x << 5, bk = blockIdx.y << 5;
  if (bn >= N || bk >= K) return;
  const float* W = p.s[z];
  ushort_t* pk = p.d[z];
  __shared__ float t[32][33];                 // [k_local][n_local]
  int tid = threadIdx.x;
  int tx = tid & 31, ty = tid >> 5;
  #pragma unroll
  for (int r = 0; r < 4; ++r)
    t[ty + (r << 3)][tx] = W[(long)(bk + ty + (r << 3)) * N + bn + tx];
  __syncthreads();
  if (tid < 128) {
    int jl = tid >> 6, q = (tid >> 4) & 3, ln = tid & 15;
    int j = (bn >> 4) + jl, kk = bk >> 5;
    long G = (((long)j * (K >> 5) + kk) << 6) + (q << 4) + ln;
    bf16x8 ov;
    #pragma unroll
    for (int e = 0; e < 8; ++e)
      ov[e] = (short)f2bs(t[(q << 3) + e][(jl << 4) + ln]);
    *(bf16x8*)(pk + (G << 3)) = ov;
  }
}

// concat 3 biases x 2 stages into f32 [2][768]
struct BC6 { const float* b[6]; };
__global__ __launch_bounds__(768)
void bias_concat_kernel(BC6 p, float* __restrict__ dst) {
  int z = blockIdx.x, tid = threadIdx.x;
  dst[z * 768 + tid] = p.b[z * 3 + (tid >> 8)][tid & 255];
}

// ---------------------------------------------------------------------------
// LayerNorm materialize: one wave per row (4 rows/block), float4 loads.
// spatial=1: source rows from query's (B,9,HW) layout, frames 0..7.
// ---------------------------------------------------------------------------
__global__ __launch_bounds__(256)
void ln_norm_kernel(const float* __restrict__ src, int spatial,
                    const float* __restrict__ g, const float* __restrict__ b,
                    ushort_t* __restrict__ dst) {
  int row = blockIdx.x * 4 + (threadIdx.x >> 6);
  int lane = threadIdx.x & 63;
  long srow = row;
  if (spatial) {
    int bq = row >> 13, r = row & 8191;
    srow = ((long)(bq * TQ_ + (r >> 10)) << 10) + (r & 1023);
  }
  float4 v = ((const float4*)(src + srow * 256))[lane];
  float s  = v.x + v.y + v.z + v.w;
  float s2 = v.x * v.x + v.y * v.y + v.z * v.z + v.w * v.w;
  #pragma unroll
  for (int m = 32; m; m >>= 1) {
    s  += __shfl_xor(s,  m, 64);
    s2 += __shfl_xor(s2, m, 64);
  }
  float mean = s * (1.f / 256.f);
  float rstd = rsqrtf(s2 * (1.f / 256.f) - mean * mean + 1e-5f);
  float4 gv = ((const float4*)g)[lane];
  float4 bv = ((const float4*)b)[lane];
  ushort_t o[4];
  o[0] = f2bs((v.x - mean) * rstd * gv.x + bv.x);
  o[1] = f2bs((v.y - mean) * rstd * gv.y + bv.y);
  o[2] = f2bs((v.z - mean) * rstd * gv.z + bv.z);
  o[3] = f2bs((v.w - mean) * rstd * gv.w + bv.w);
  u32 lo = (u32)o[0] | ((u32)o[1] << 16);
  u32 hi = (u32)o[2] | ((u32)o[3] << 16);
  uint2 pk; pk.x = lo; pk.y = hi;
  *(uint2*)(dst + (long)row * 256 + lane * 4) = pk;
}

// ---------------------------------------------------------------------------
// Weights-resident streaming GEMM.
//   C[M, N] = A[M, K](lda, bf16) @ W^T + bias (+rope)(+gelu)(+resid)
// Block = 256 thr (4 waves), tile = 128 rows x NCH cols (NCH = NF*64).
// grid (M/128, N/NCH).  gridDim.x % 8 == 0 -> blocks sharing an A panel land
// on the same XCD (L2-local); the 4 waves split N, so their (identical) A
// fragment loads hit L1.
// Packed weight chunk (NCH*K*2 B) is staged into LDS ONCE (linear copy via
// global_load_lds), then the K-loop has NO barriers: A streams global->reg
// with a 2-deep ping-pong so the compiler emits counted vmcnt waits and each
// wave keeps ~8KB in flight continuously (vs ~4KB gated by 2 barriers/K-step
// in the old structure). LDS B reads are lane-linear 16B: conflict-free.
// resid_mode: 0 none, 1 f32 contiguous [m][256], 2 f32 query spatial-mapped
// out_mode:   0 f32 [m][N], 1 f32 spatial->9-frame map [orow][256], 2 bf16 [m][N]
// rope: split-half RoPE on cols n<512 (heads of 32); NF==2 only.
// ---------------------------------------------------------------------------
template<int NF, int K>
__global__ __launch_bounds__(256, 2)
void wgemm_kernel(const ushort_t* __restrict__ A, int lda,
                  const ushort_t* __restrict__ packW,
                  const float* __restrict__ bias, const float* __restrict__ resid,
                  float* __restrict__ Cf, ushort_t* __restrict__ Cb,
                  int N, int resid_mode, int out_mode, int act, int rope) {
  constexpr int K32 = K / 32;
  constexpr int NCH = NF * 64;
  __shared__ ushort_t Wl[NCH * K];            // 64KB (NF=2,K=256) / 128KB (NF=1,K=1024)
  int tid = threadIdx.x;
  int wv = tid >> 6, lane = tid & 63;
  int ln = lane & 15, q = lane >> 4;
  int m0 = blockIdx.x << 7;
  int n0 = blockIdx.y * NCH;

  // ---- stage packed weight chunk: straight linear HBM->LDS copy ----
  const ushort_t* src = packW + (long)blockIdx.y * (NCH * K);
  constexpr int NSTG = (NCH * K) / (8 * 256);
  #pragma unroll
  for (int i = 0; i < NSTG; ++i) {
    int g0 = (i << 8) + (wv << 6);
    gload16(src + ((long)(g0 + lane) << 3), Wl + ((long)g0 << 3));
  }

  const ushort_t* Ap = A + (long)(m0 + ln) * lda + (q << 3);
  long rstr = (long)lda << 4;                 // 16-row stride (elements)

  f32x4 acc[8][NF];
  #pragma unroll
  for (int i = 0; i < 8; ++i)
    #pragma unroll
    for (int jl = 0; jl < NF; ++jl) acc[i][jl] = 0.f;

  // first A fragments issued before the stage drain (overlap)
  bf16x8 a0[8], a1[8];
  #pragma unroll
  for (int i = 0; i < 8; ++i) a0[i] = *(const bf16x8*)(Ap + i * rstr);

  __builtin_amdgcn_s_waitcnt(WAIT_VMCNT0);
  __builtin_amdgcn_s_barrier();               // the ONLY barrier

  #pragma unroll 1
  for (int kk = 0; kk < K32; kk += 2) {
    #pragma unroll
    for (int i = 0; i < 8; ++i)
      a1[i] = *(const bf16x8*)(Ap + i * rstr + (kk + 1) * 32);
    bf16x8 b0[NF];
    #pragma unroll
    for (int jl = 0; jl < NF; ++jl)
      b0[jl] = *(const bf16x8*)&Wl[(((wv * NF + jl) * K32 + kk) << 9) + (lane << 3)];
    #pragma unroll
    for (int i = 0; i < 8; ++i)
      #pragma unroll
      for (int jl = 0; jl < NF; ++jl)
        acc[i][jl] = __builtin_amdgcn_mfma_f32_16x16x32_bf16(a0[i], b0[jl], acc[i][jl], 0, 0, 0);
    if (kk + 2 < K32) {
      #pragma unroll
      for (int i = 0; i < 8; ++i)
        a0[i] = *(const bf16x8*)(Ap + i * rstr + (kk + 2) * 32);
    }
    bf16x8 b1[NF];
    #pragma unroll
    for (int jl = 0; jl < NF; ++jl)
      b1[jl] = *(const bf16x8*)&Wl[(((wv * NF + jl) * K32 + kk + 1) << 9) + (lane << 3)];
    #pragma unroll
    for (int i = 0; i < 8; ++i)
      #pragma unroll
      for (int jl = 0; jl < NF; ++jl)
        acc[i][jl] = __builtin_amdgcn_mfma_f32_16x16x32_bf16(a1[i], b1[jl], acc[i][jl], 0, 0, 0);
  }

  // ---- epilogue ----
  float bv[NF];
  #pragma unroll
  for (int jl = 0; jl < NF; ++jl)
    bv[jl] = bias[n0 + ((wv * NF + jl) << 4) + ln];

  float c_ = 1.f, s_ = 0.f;
  int rope_on = 0;
  if (NF == 2 && rope && (n0 + (wv << 5)) < 512) {
    int t = (m0 >> 10) % TQ_;                 // tile lies within one 1024-row block
    float ang = (float)t * exp2f((float)ln * -0.8304820237218406f);
    c_ = cosf(ang); s_ = sinf(ang); rope_on = 1;
  }

  #pragma unroll
  for (int i = 0; i < 8; ++i) {
    int mb = m0 + (i << 4) + (q << 2);
    float v[NF][4];
    #pragma unroll
    for (int jl = 0; jl < NF; ++jl)
      #pragma unroll
      for (int r = 0; r < 4; ++r) v[jl][r] = acc[i][jl][r] + bv[jl];
    if (NF == 2 && rope_on) {
      #pragma unroll
      for (int r = 0; r < 4; ++r) {
        float x1 = v[0][r], x2 = v[NF - 1][r];
        v[0][r]      = x1 * c_ - x2 * s_;
        v[NF - 1][r] = x1 * s_ + x2 * c_;
      }
    }
    if (act) {
      #pragma unroll
      for (int jl = 0; jl < NF; ++jl)
        #pragma unroll
        for (int r = 0; r < 4; ++r) {
          float x = v[jl][r];
          v[jl][r] = 0.5f * x * (1.f + erff(x * 0.70710678118654752f));
        }
    }
    #pragma unroll
    for (int r = 0; r < 4; ++r) {
      int m = mb + r;
      long orow = m;
      if (out_mode == 1 || resid_mode == 2) {
        int bq = m >> 13, rr = m & 8191;
        orow = ((long)(bq * TQ_ + (rr >> 10)) << 10) + (rr & 1023);
      }
      #pragma unroll
      for (int jl = 0; jl < NF; ++jl) {
        int n = n0 + ((wv * NF + jl) << 4) + ln;
        float x = v[jl][r];
        if (resid_mode == 1)      x += resid[(long)m * 256 + n];
        else if (resid_mode == 2) x += resid[orow * 256 + n];
        if (out_mode == 2)      Cb[(long)m * N + n] = f2bs(x);
        else if (out_mode == 1) Cf[orow * 256 + n] = x;
        else                    Cf[(long)m * N + n] = x;
      }
    }
  }
}

// ---------------------------------------------------------------------------
// Spatial 3x3 windowed attention on packed QKV [m][768] bf16. One thread per
// (pixel, head), head-fast -> per-wave 8 pixels x 8 heads (coalesced 512B
// segments). o over q in-place.
// ---------------------------------------------------------------------------
__global__ __launch_bounds__(256)
void spatial_attn_kernel(ushort_t* __restrict__ qkv) {
  int gid = blockIdx.x * 256 + threadIdx.x;   // 262144
  int head = gid & 7, pixel = gid >> 3;
  int pix = pixel & 1023, bt = pixel >> 10;
  int y = pix >> 5, x = pix & 31;
  long rb = (long)bt << 10;
  const float scale = 0.17677669529663687f;   // 1/sqrt(32)

  float qf[32];
  long qoff = (long)pixel * 768 + head * 32;
  #pragma unroll
  for (int i = 0; i < 4; ++i) {
    bf16x8 t = *(const bf16x8*)(qkv + qoff + i * 8);
    #pragma unroll
    for (int e = 0; e < 8; ++e) qf[i * 8 + e] = bs2f((ushort_t)t[e]);
  }

  float s[9];
  bool val[9];
  #pragma unroll
  for (int n = 0; n < 9; ++n) {
    int yy = y + n / 3 - 1, xx = x + n % 3 - 1;
    bool ok = ((unsigned)yy < 32u) & ((unsigned)xx < 32u);
    val[n] = ok;
    float d = 0.f;
    if (ok) {
      long ko = (rb + (yy << 5) + xx) * 768 + 256 + head * 32;
      #pragma unroll
      for (int i = 0; i < 4; ++i) {
        bf16x8 t = *(const bf16x8*)(qkv + ko + i * 8);
        #pragma unroll
        for (int e = 0; e < 8; ++e) d += qf[i * 8 + e] * bs2f((ushort_t)t[e]);
      }
    }
    s[n] = d * scale;
  }
  float mx = -1e30f;
  #pragma unroll
  for (int n = 0; n < 9; ++n) if (val[n]) mx = fmaxf(mx, s[n]);
  float sum = 0.f;
  #pragma unroll
  for (int n = 0; n < 9; ++n) { s[n] = val[n] ? __expf(s[n] - mx) : 0.f; sum += s[n]; }
  float inv = 1.f / sum;

  float o[32];
  #pragma unroll
  for (int i = 0; i < 32; ++i) o[i] = 0.f;
  #pragma unroll
  for (int n = 0; n < 9; ++n) {
    if (val[n]) {
      int yy = y + n / 3 - 1, xx = x + n % 3 - 1;
      long vo = (rb + (yy << 5) + xx) * 768 + 512 + head * 32;
      #pragma unroll
      for (int i = 0; i < 4; ++i) {
        bf16x8 t = *(const bf16x8*)(qkv + vo + i * 8);
        #pragma unroll
        for (int e = 0; e < 8; ++e) o[i * 8 + e] += s[n] * bs2f((ushort_t)t[e]);
      }
    }
  }
  #pragma unroll
  for (int i = 0; i < 4; ++i) {
    bf16x8 t;
    #pragma unroll
    for (int e = 0; e < 8; ++e) t[e] = (short)f2bs(o[i * 8 + e] * inv);
    *(bf16x8*)(qkv + qoff + i * 8) = t;
  }
}

// ---------------------------------------------------------------------------
// Temporal attention (full 9x9; mask all-False). Head-fast: thread =
// (hw-in-group, head); block = (tq, b, hw-group). o over q in-place.
// ---------------------------------------------------------------------------
__global__ __launch_bounds__(256)
void temporal_attn_kernel(ushort_t* __restrict__ qkv) {
  int tid = threadIdx.x;
  int head = tid & 7, hwi = tid >> 3;
  int bi = blockIdx.x;                          // 1152 = 9 * 4 * 32
  int tq = bi >> 7;
  int rest = bi & 127;
  int b = rest >> 5, hwg = rest & 31;
  int hw = (hwg << 5) + hwi;
  long base = (long)(b * TQ_) * 1024 + hw;
  const float scale = 0.17677669529663687f;

  float qf[32];
  long qoff = (base + (long)tq * 1024) * 768 + head * 32;
  #pragma unroll
  for (int i = 0; i < 4; ++i) {
    bf16x8 t = *(const bf16x8*)(qkv + qoff + i * 8);
    #pragma unroll
    for (int e = 0; e < 8; ++e) qf[i * 8 + e] = bs2f((ushort_t)t[e]);
  }
  float s[9];
  #pragma unroll
  for (int tk = 0; tk < 9; ++tk) {
    long ko = (base + (long)tk * 1024) * 768 + 256 + head * 32;
    float d = 0.f;
    #pragma unroll
    for (int i = 0; i < 4; ++i) {
      bf16x8 t = *(const bf16x8*)(qkv + ko + i * 8);
      #pragma unroll
      for (int e = 0; e < 8; ++e) d += qf[i * 8 + e] * bs2f((ushort_t)t[e]);
    }
    s[tk] = d * scale;
  }
  float mx = s[0];
  #pragma unroll
  for (int tk = 1; tk < 9; ++tk) mx = fmaxf(mx, s[tk]);
  float sum = 0.f;
  #pragma unroll
  for (int tk = 0; tk < 9; ++tk) { s[tk] = __expf(s[tk] - mx); sum += s[tk]; }
  float inv = 1.f / sum;

  float o[32];
  #pragma unroll
  for (int i = 0; i < 32; ++i) o[i] = 0.f;
  #pragma unroll
  for (int tk = 0; tk < 9; ++tk) {
    long vo = (base + (long)tk * 1024) * 768 + 512 + head * 32;
    #pragma unroll
    for (int i = 0; i < 4; ++i) {
      bf16x8 t = *(const bf16x8*)(qkv + vo + i * 8);
      #pragma unroll
      for (int e = 0; e < 8; ++e) o[i * 8 + e] += s[tk] * bs2f((ushort_t)t[e]);
    }
  }
  #pragma unroll
  for (int i = 0; i < 4; ++i) {
    bf16x8 t;
    #pragma unroll
    for (int e = 0; e < 8; ++e) t[e] = (short)f2bs(o[i * 8 + e] * inv);
    *(bf16x8*)(qkv + qoff + i * 8) = t;
  }
}

// copy query frame 8 into x (f32); identical linear indices in both buffers
__global__ __launch_bounds__(256)
void copy_frame8_kernel(const float* __restrict__ qy, float* __restrict__ x) {
  long i = (long)blockIdx.x * 256 + threadIdx.x;
  int b = (int)(i >> 18);
  long rem = i & ((1L << 18) - 1);
  long gi = ((long)(b * TQ_ + 8) << 18) + rem;
  x[gi] = qy[gi];
}

// CLS frame mean over spatial: partial sums then broadcast (on f32 x)
__global__ __launch_bounds__(256)
void cls_sum_kernel(const float* __restrict__ x, float* __restrict__ partial) {
  int b = blockIdx.x >> 5, ch = blockIdx.x & 31;
  int d = threadIdx.x;
  long base = ((long)(b * TQ_) * 1024 + ch * 32) * 256 + d;
  float s = 0.f;
  for (int r = 0; r < 32; ++r) s += x[base + (long)r * 256];
  partial[(long)blockIdx.x * 256 + d] = s;
}

__global__ __launch_bounds__(256)
void cls_bcast_kernel(float* __restrict__ x, const float* __restrict__ partial) {
  int b = blockIdx.x >> 3, seg = blockIdx.x & 7;
  int d = threadIdx.x;
  float s = 0.f;
  for (int j = 0; j < 32; ++j) s += partial[(long)(b * 32 + j) * 256 + d];
  s *= (1.f / 1024.f);
  long base = ((long)(b * TQ_) * 1024 + seg * 128) * 256 + d;
  for (int r = 0; r < 128; ++r) x[base + (long)r * 256] = s;
}

// ---------------------------------------------------------------------------
extern "C" void kernel_launch(void* const* d_in, const int* in_sizes, int n_in,
                              void* d_out, int out_size, void* d_ws, size_t ws_size,
                              hipStream_t stream) {
  (void)in_sizes; (void)n_in; (void)out_size; (void)ws_size;
  const float* query = (const float*)d_in[0];
  const float* sln_g = (const float*)d_in[3];
  const float* sln_b = (const float*)d_in[4];
  const float* s_wq  = (const float*)d_in[5];
  const float* s_bq  = (const float*)d_in[6];
  const float* s_wk  = (const float*)d_in[7];
  const float* s_bk  = (const float*)d_in[8];
  const float* s_wv  = (const float*)d_in[9];
  const float* s_bv  = (const float*)d_in[10];
  const float* s_wo  = (const float*)d_in[11];
  const float* s_bo  = (const float*)d_in[12];
  const float* tln_g = (const float*)d_in[13];
  const float* tln_b = (const float*)d_in[14];
  const float* t_wq  = (const float*)d_in[15];
  const float* t_bq  = (const float*)d_in[16];
  const float* t_wk  = (const float*)d_in[17];
  const float* t_bk  = (const float*)d_in[18];
  const float* t_wv  = (const float*)d_in[19];
  const float* t_bv  = (const float*)d_in[20];
  const float* t_wo  = (const float*)d_in[21];
  const float* t_bo  = (const float*)d_in[22];
  const float* mln_g = (const float*)d_in[23];
  const float* mln_b = (const float*)d_in[24];
  const float* w1    = (const float*)d_in[25];
  const float* b1    = (const float*)d_in[26];
  const float* w2    = (const float*)d_in[27];
  const float* b2    = (const float*)d_in[28];
  float* out = (float*)d_out;

  // ---- workspace (~115.4 MB) ----
  const long RB = 36864L * 256;
  ushort_t* XA  = (ushort_t*)d_ws;          // RB bf16
  ushort_t* QKV = XA + RB;                  // 3*RB bf16, rows of 768
  float*    P4  = (float*)(QKV + 3 * RB);   // RB f32 (free during MLP)
  ushort_t* wt  = (ushort_t*)(P4 + RB);     // 2 MB packed weights
  float* bias2  = (float*)(wt + 1048576);   // 2x768 f32
  float* clsp   = bias2 + 1536;             // 128*256 f32
  // MLP hidden: 36864x1024 bf16 = 75.5 MB, spans QKV (56.6) + P4 (first half)
  ushort_t* hid = QKV;

  ushort_t* pk_sqkv = wt;                   // packed [768][256]
  ushort_t* pk_tqkv = wt + 196608;          // packed [768][256]
  ushort_t* pk_swo  = wt + 393216;          // packed [256][256]
  ushort_t* pk_two  = wt + 458752;          // packed [256][256]
  ushort_t* pk_w1   = wt + 524288;          // packed [1024][256]
  ushort_t* pk_w2   = wt + 786432;          // packed [256][1024]

  // ---- weight / bias prep (one pack dispatch) ----
  TPA tp;
  tp.s[0] = s_wq; tp.d[0] = pk_sqkv;          tp.K[0] = 256;  tp.N[0] = 256;
  tp.s[1] = s_wk; tp.d[1] = pk_sqkv + 65536;  tp.K[1] = 256;  tp.N[1] = 256;
  tp.s[2] = s_wv; tp.d[2] = pk_sqkv + 131072; tp.K[2] = 256;  tp.N[2] = 256;
  tp.s[3] = t_wq; tp.d[3] = pk_tqkv;          tp.K[3] = 256;  tp.N[3] = 256;
  tp.s[4] = t_wk; tp.d[4] = pk_tqkv + 65536;  tp.K[4] = 256;  tp.N[4] = 256;
  tp.s[5] = t_wv; tp.d[5] = pk_tqkv + 131072; tp.K[5] = 256;  tp.N[5] = 256;
  tp.s[6] = s_wo; tp.d[6] = pk_swo;           tp.K[6] = 256;  tp.N[6] = 256;
  tp.s[7] = t_wo; tp.d[7] = pk_two;           tp.K[7] = 256;  tp.N[7] = 256;
  tp.s[8] = w1;   tp.d[8] = pk_w1;            tp.K[8] = 256;  tp.N[8] = 1024;
  tp.s[9] = w2;   tp.d[9] = pk_w2;            tp.K[9] = 1024; tp.N[9] = 256;
  pack_all_kernel<<<dim3(32, 32, 10), 256, 0, stream>>>(tp);
  BC6 bc;
  bc.b[0] = s_bq; bc.b[1] = s_bk; bc.b[2] = s_bv;
  bc.b[3] = t_bq; bc.b[4] = t_bk; bc.b[5] = t_bv;
  bias_concat_kernel<<<2, 768, 0, stream>>>(bc, bias2);

  // ---- spatial windowed attention (frames 0..7), M=32768 ----
  ln_norm_kernel<<<8192, 256, 0, stream>>>(query, 1, sln_g, sln_b, XA);
  wgemm_kernel<2, 256><<<dim3(256, 6), 256, 0, stream>>>(
      XA, 256, pk_sqkv, bias2, nullptr, nullptr, QKV, 768, 0, 2, 0, 0);
  spatial_attn_kernel<<<1024, 256, 0, stream>>>(QKV);
  wgemm_kernel<2, 256><<<dim3(256, 2), 256, 0, stream>>>(
      QKV, 768, pk_swo, s_bo, query, P4, nullptr, 256, 2, 1, 0, 0);
  copy_frame8_kernel<<<4096, 256, 0, stream>>>(query, P4);

  // ---- temporal RoPE attention, M=36864 ----
  ln_norm_kernel<<<9216, 256, 0, stream>>>(P4, 0, tln_g, tln_b, XA);
  wgemm_kernel<2, 256><<<dim3(288, 6), 256, 0, stream>>>(
      XA, 256, pk_tqkv, bias2 + 768, nullptr, nullptr, QKV, 768, 0, 2, 0, 1);
  temporal_attn_kernel<<<1152, 256, 0, stream>>>(QKV);
  wgemm_kernel<2, 256><<<dim3(288, 2), 256, 0, stream>>>(
      QKV, 768, pk_two, t_bo, P4, out, nullptr, 256, 1, 0, 0, 0);

  // ---- CLS frame spatial mean + broadcast (on out = x2) ----
  cls_sum_kernel<<<128, 256, 0, stream>>>(out, clsp);
  cls_bcast_kernel<<<32, 256, 0, stream>>>(out, clsp);

  // ---- MLP, full-M (hid spans QKV+P4) ----
  ln_norm_kernel<<<9216, 256, 0, stream>>>(out, 0, mln_g, mln_b, XA);
  wgemm_kernel<2, 256><<<dim3(288, 8), 256, 0, stream>>>(
      XA, 256, pk_w1, b1, nullptr, nullptr, hid, 1024, 0, 2, 1, 0);
  wgemm_kernel<1, 1024><<<dim3(288, 4), 256, 0, stream>>>(
      hid, 1024, pk_w2, b2, out, out, nullptr, 256, 1, 0, 0, 0);
}

// Round 2
// 614.649 us; speedup vs baseline: 1.3133x; 1.3133x over previous
//
#include <hip/hip_runtime.h>
#include <math.h>

#define TQ_  9

typedef unsigned int   u32;
typedef unsigned short ushort_t;
typedef short bf16x8 __attribute__((ext_vector_type(8)));
typedef float f32x4  __attribute__((ext_vector_type(4)));

// s_waitcnt imm: expcnt=7(ignored), lgkmcnt=15(ignored), vmcnt=N (N<=15)
#define WVM(n) __builtin_amdgcn_s_waitcnt(0x0F70 | (n))

__device__ __forceinline__ float bs2f(ushort_t s) {
  return __uint_as_float(((u32)s) << 16);
}
__device__ __forceinline__ ushort_t f2bs(float x) {   // round-to-nearest-even
  u32 u = __float_as_uint(x);
  u32 r = (u + 0x7FFFu + ((u >> 16) & 1u)) >> 16;
  return (ushort_t)r;
}
__device__ __forceinline__ void gload16(const void* g, void* l) {
  __builtin_amdgcn_global_load_lds((const __attribute__((address_space(1))) u32*)g,
                                   (__attribute__((address_space(3))) u32*)l, 16, 0, 0);
}

// ---------------------------------------------------------------------------
// Weight PACK: W f32 [K][N] -> MFMA-B-frag-linear bf16.
// Frag group G = (j*(K/32) + kk)*64 + q*16 + ln holds 8 bf16:
//   element e: out-col n = j*16+ln, k = kk*32 + q*8 + e.
// pm=1 (Q/K weights): out-columns permuted within each 32-col head so RoPE
// pairs (d, d+16) sit at lanes ln, ln^8 of one 16-col chunk:
//   source col local = (ln&7) + 8*(j&1) + 16*(ln>>3).
// Q·K dot products are invariant to this common permutation.
// ---------------------------------------------------------------------------
struct TPA { const float* s[10]; ushort_t* d[10]; int K[10]; int N[10]; int pm[10]; };

__global__ __launch_bounds__(256)
void pack_all_kernel(TPA p) {
  int z = blockIdx.z;
  int K = p.K[z], N = p.N[z];
  int bn = blockIdx.x << 5, bk = blockIdx.y << 5;
  if (bn >= N || bk >= K) return;
  const float* W = p.s[z];
  ushort_t* pk = p.d[z];
  int pm = p.pm[z];
  __shared__ float t[32][33];                 // [k_local][n_local]
  int tid = threadIdx.x;
  int tx = tid & 31, ty = tid >> 5;
  #pragma unroll
  for (int r = 0; r < 4; ++r)
    t[ty + (r << 3)][tx] = W[(long)(bk + ty + (r << 3)) * N + bn + tx];
  __syncthreads();
  if (tid < 128) {
    int jl = tid >> 6, q = (tid >> 4) & 3, ln = tid & 15;
    int j = (bn >> 4) + jl, kk = bk >> 5;
    int colsrc = pm ? ((ln & 7) + (jl << 3) + ((ln & 8) << 1))
                    : ((jl << 4) + ln);
    long G = (((long)j * (K >> 5) + kk) << 6) + (q << 4) + ln;
    bf16x8 ov;
    #pragma unroll
    for (int e = 0; e < 8; ++e)
      ov[e] = (short)f2bs(t[(q << 3) + e][colsrc]);
    *(bf16x8*)(pk + (G << 3)) = ov;
  }
}

// concat 3 biases x 2 stages into f32 [2][768]; Q/K parts permuted to match
struct BC6 { const float* b[6]; };
__global__ __launch_bounds__(768)
void bias_concat_kernel(BC6 p, float* __restrict__ dst) {
  int z = blockIdx.x, n = threadIdx.x;
  int w = n >> 8, q = n & 255;
  int psrc = q;
  if (w < 2)
    psrc = (q & 0xE0) | (q & 7) | (((q >> 4) & 1) << 3) | (((q >> 3) & 1) << 4);
  dst[z * 768 + n] = p.b[z * 3 + w][psrc];
}

// ---------------------------------------------------------------------------
// LayerNorm materialize: one wave per row (4 rows/block), float4 loads.
// ---------------------------------------------------------------------------
__global__ __launch_bounds__(256)
void ln_norm_kernel(const float* __restrict__ src, int spatial,
                    const float* __restrict__ g, const float* __restrict__ b,
                    ushort_t* __restrict__ dst) {
  int row = blockIdx.x * 4 + (threadIdx.x >> 6);
  int lane = threadIdx.x & 63;
  long srow = row;
  if (spatial) {
    int bq = row >> 13, r = row & 8191;
    srow = ((long)(bq * TQ_ + (r >> 10)) << 10) + (r & 1023);
  }
  float4 v = ((const float4*)(src + srow * 256))[lane];
  float s  = v.x + v.y + v.z + v.w;
  float s2 = v.x * v.x + v.y * v.y + v.z * v.z + v.w * v.w;
  #pragma unroll
  for (int m = 32; m; m >>= 1) {
    s  += __shfl_xor(s,  m, 64);
    s2 += __shfl_xor(s2, m, 64);
  }
  float mean = s * (1.f / 256.f);
  float rstd = rsqrtf(s2 * (1.f / 256.f) - mean * mean + 1e-5f);
  float4 gv = ((const float4*)g)[lane];
  float4 bv = ((const float4*)b)[lane];
  ushort_t o[4];
  o[0] = f2bs((v.x - mean) * rstd * gv.x + bv.x);
  o[1] = f2bs((v.y - mean) * rstd * gv.y + bv.y);
  o[2] = f2bs((v.z - mean) * rstd * gv.z + bv.z);
  o[3] = f2bs((v.w - mean) * rstd * gv.w + bv.w);
  u32 lo = (u32)o[0] | ((u32)o[1] << 16);
  u32 hi = (u32)o[2] | ((u32)o[3] << 16);
  uint2 pk; pk.x = lo; pk.y = hi;
  *(uint2*)(dst + (long)row * 256 + lane * 4) = pk;
}

// ---------------------------------------------------------------------------
// Weights-resident streaming GEMM, LDS-DMA pipelined (T3/T4 counted vmcnt).
//   C[M,N] = A[M,K](lda, bf16) @ W^T + bias (+rope)(+gelu)(+resid)
// Block: 128 rows x 64 cols, 4 waves x 16 cols, 1-D grid with XCD-grouping
// swizzle: group of 32 ids = 8 m-panels x 4 n-chunks; same-panel blocks land
// on one XCD within 32 ids -> A panel HBM-fetched once, L2-served after.
// A: 4-buffer LDS ring (8KB/step), global_load_lds, prefetch 3, exact vmcnt
// ladder, ONE barrier/step, loads in flight across barriers (never drained).
// A k-slot XOR swizzle (source-side, rule both-sides): 8-way -> 4-way b128.
// W: K=256 fully resident (32KB); K=1024 triple-buffered 16KB phases staged
// 2 phases ahead, 1 instr/wave/step interleaved into the A pipeline.
// LDS total 64/80 KB -> 2 blocks/CU (8 waves/CU); ~48KB/CU DMA in flight.
// rope: permuted-pair RoPE via __shfl_xor(8) on chunks jglb<32.
// ---------------------------------------------------------------------------
template<int K>
__global__ __launch_bounds__(256, 2)
void wgemm_kernel(const ushort_t* __restrict__ A, int lda,
                  const ushort_t* __restrict__ packW,
                  const float* __restrict__ bias, const float* __restrict__ resid,
                  float* __restrict__ Cf, ushort_t* __restrict__ Cb,
                  int N, int NBq, int resid_mode, int out_mode, int act, int rope) {
  constexpr int K32 = K / 32;
  constexpr bool PH = (K32 > 8);
  constexpr int WELEM = PH ? 3 * 16 * 512 : 4 * K32 * 512;
  __shared__ ushort_t Abuf[4][4096];          // 4 x 8KB ring
  __shared__ ushort_t Wbuf[WELEM];            // 32KB resident / 3x16KB ring

  int tid = threadIdx.x;
  int wv = tid >> 6, lane = tid & 63;
  int ln = lane & 15, q4 = lane >> 4;

  // XCD-grouping decode
  int gid = blockIdx.x;
  int g = gid >> 5, r = gid & 31;
  int nq = (r >> 3) + ((g % NBq) << 2);
  int mb = ((g / NBq) << 3) + (r & 7);
  int m0 = mb << 7, n0 = nq << 6;

  // A stage source (per-lane, k-slot XOR pre-swizzled on the global side)
  int arow = lane >> 2;
  int aq = (lane & 3) ^ (arow & 3);
  const ushort_t* As0 = A + (long)(m0 + (wv << 5) + arow) * lda + (aq << 3);
  const ushort_t* As1 = As0 + (long)lda * 16;

  // W stage source: wave wv owns col-chunk j = nq*4+wv
  const ushort_t* Ws = packW + (((long)(nq * 4 + wv) * K32) << 9) + (lane << 3);

  // ---- prologue: W (8 instr) then A steps 0..2 (6 instr) ----
  if (PH) {
    #pragma unroll
    for (int s = 0; s < 8; ++s)
      gload16(Ws + (s << 9), &Wbuf[((s >> 2) * 16 + wv * 4 + (s & 3)) << 9]);
  } else {
    #pragma unroll
    for (int kk = 0; kk < K32; ++kk)
      gload16(Ws + (kk << 9), &Wbuf[(wv * K32 + kk) << 9]);
  }
  #pragma unroll
  for (int kk = 0; kk < 3; ++kk) {
    gload16(As0 + kk * 32, &Abuf[kk][(wv * 2) << 9]);
    gload16(As1 + kk * 32, &Abuf[kk][(wv * 2 + 1) << 9]);
  }

  f32x4 acc[8];
  #pragma unroll
  for (int i = 0; i < 8; ++i) acc[i] = 0.f;

  int abase = ln * 32 + ((q4 ^ (ln & 3)) << 3);   // swizzled read slot

  #pragma unroll 1
  for (int kk = 0; kk < K32; ++kk) {
    // exact counted vmcnt ladder: wait for MY step-kk stage instrs only;
    // the barrier then makes everyone's step-kk data visible.
    if (PH) {
      if (kk < 3)              WVM(4);
      else if (kk <= K32 - 8)  WVM(7);
      else if (kk <= K32 - 3)  WVM(2);
      else                     WVM(0);
    } else {
      if (kk <= K32 - 3)       WVM(4);
      else if (kk == K32 - 2)  WVM(2);
      else                     WVM(0);
    }
    __builtin_amdgcn_s_barrier();
    if (kk + 3 < K32) {                         // A prefetch (ring slot free)
      gload16(As0 + (kk + 3) * 32, &Abuf[(kk + 3) & 3][(wv * 2) << 9]);
      gload16(As1 + (kk + 3) * 32, &Abuf[(kk + 3) & 3][(wv * 2 + 1) << 9]);
    }
    if (PH && kk + 8 < K32)                     // W slice, 2 phases ahead
      gload16(Ws + ((kk + 8) << 9),
              &Wbuf[((((kk + 8) >> 2) % 3) * 16 + wv * 4 + ((kk + 8) & 3)) << 9]);
    const ushort_t* ab = &Abuf[kk & 3][abase];
    bf16x8 bfr = *(const bf16x8*)&Wbuf[(PH ? ((((kk >> 2) % 3) * 16 + wv * 4 + (kk & 3)) << 9)
                                           : ((wv * K32 + kk) << 9)) + (lane << 3)];
    #pragma unroll
    for (int i = 0; i < 8; ++i) {
      bf16x8 af = *(const bf16x8*)(ab + (i << 9));
      acc[i] = __builtin_amdgcn_mfma_f32_16x16x32_bf16(af, bfr, acc[i], 0, 0, 0);
    }
  }

  // ---- epilogue ----
  float bvx = bias[n0 + (wv << 4) + ln];
  int jglb = (nq << 2) + wv;
  float c_ = 1.f, ss_ = 0.f;
  bool ropeon = rope && (jglb < 32);
  if (ropeon) {
    int t = (m0 >> 10) % TQ_;
    int d = (ln & 7) + ((jglb & 1) << 3);
    float ang = (float)t * exp2f((float)d * -0.8304820237218406f);
    c_ = cosf(ang);
    float s_ = sinf(ang);
    ss_ = (ln & 8) ? s_ : -s_;                  // x1-lane: -s, x2-lane: +s
  }

  #pragma unroll
  for (int i = 0; i < 8; ++i) {
    int mbase = m0 + (i << 4) + (q4 << 2);
    float v[4];
    #pragma unroll
    for (int r2 = 0; r2 < 4; ++r2) v[r2] = acc[i][r2] + bvx;
    if (ropeon) {
      #pragma unroll
      for (int r2 = 0; r2 < 4; ++r2) {
        float other = __shfl_xor(v[r2], 8, 64); // pair partner (same row)
        v[r2] = v[r2] * c_ + other * ss_;
      }
    }
    if (act) {
      #pragma unroll
      for (int r2 = 0; r2 < 4; ++r2) {
        float x = v[r2];
        v[r2] = 0.5f * x * (1.f + erff(x * 0.70710678118654752f));
      }
    }
    #pragma unroll
    for (int r2 = 0; r2 < 4; ++r2) {
      int m = mbase + r2;
      long orow = m;
      if (out_mode == 1 || resid_mode == 2) {
        int bq = m >> 13, rr = m & 8191;
        orow = ((long)(bq * TQ_ + (rr >> 10)) << 10) + (rr & 1023);
      }
      int n = n0 + (wv << 4) + ln;
      float x = v[r2];
      if (resid_mode == 1)      x += resid[(long)m * 256 + n];
      else if (resid_mode == 2) x += resid[orow * 256 + n];
      if (out_mode == 2)      Cb[(long)m * N + n] = f2bs(x);
      else if (out_mode == 1) Cf[orow * 256 + n] = x;
      else                    Cf[(long)m * N + n] = x;
    }
  }
}

// ---------------------------------------------------------------------------
// Spatial 3x3 windowed attention on packed QKV [m][768] bf16. One thread per
// (pixel, head), head-fast. o over q in-place. (Q/K head-dim permutation is
// common to q and k -> dot products unchanged.)
// ---------------------------------------------------------------------------
__global__ __launch_bounds__(256)
void spatial_attn_kernel(ushort_t* __restrict__ qkv) {
  int gid = blockIdx.x * 256 + threadIdx.x;   // 262144
  int head = gid & 7, pixel = gid >> 3;
  int pix = pixel & 1023, bt = pixel >> 10;
  int y = pix >> 5, x = pix & 31;
  long rb = (long)bt << 10;
  const float scale = 0.17677669529663687f;   // 1/sqrt(32)

  float qf[32];
  long qoff = (long)pixel * 768 + head * 32;
  #pragma unroll
  for (int i = 0; i < 4; ++i) {
    bf16x8 t = *(const bf16x8*)(qkv + qoff + i * 8);
    #pragma unroll
    for (int e = 0; e < 8; ++e) qf[i * 8 + e] = bs2f((ushort_t)t[e]);
  }

  float s[9];
  bool val[9];
  #pragma unroll
  for (int n = 0; n < 9; ++n) {
    int yy = y + n / 3 - 1, xx = x + n % 3 - 1;
    bool ok = ((unsigned)yy < 32u) & ((unsigned)xx < 32u);
    val[n] = ok;
    float d = 0.f;
    if (ok) {
      long ko = (rb + (yy << 5) + xx) * 768 + 256 + head * 32;
      #pragma unroll
      for (int i = 0; i < 4; ++i) {
        bf16x8 t = *(const bf16x8*)(qkv + ko + i * 8);
        #pragma unroll
        for (int e = 0; e < 8; ++e) d += qf[i * 8 + e] * bs2f((ushort_t)t[e]);
      }
    }
    s[n] = d * scale;
  }
  float mx = -1e30f;
  #pragma unroll
  for (int n = 0; n < 9; ++n) if (val[n]) mx = fmaxf(mx, s[n]);
  float sum = 0.f;
  #pragma unroll
  for (int n = 0; n < 9; ++n) { s[n] = val[n] ? __expf(s[n] - mx) : 0.f; sum += s[n]; }
  float inv = 1.f / sum;

  float o[32];
  #pragma unroll
  for (int i = 0; i < 32; ++i) o[i] = 0.f;
  #pragma unroll
  for (int n = 0; n < 9; ++n) {
    if (val[n]) {
      int yy = y + n / 3 - 1, xx = x + n % 3 - 1;
      long vo = (rb + (yy << 5) + xx) * 768 + 512 + head * 32;
      #pragma unroll
      for (int i = 0; i < 4; ++i) {
        bf16x8 t = *(const bf16x8*)(qkv + vo + i * 8);
        #pragma unroll
        for (int e = 0; e < 8; ++e) o[i * 8 + e] += s[n] * bs2f((ushort_t)t[e]);
      }
    }
  }
  #pragma unroll
  for (int i = 0; i < 4; ++i) {
    bf16x8 t;
    #pragma unroll
    for (int e = 0; e < 8; ++e) t[e] = (short)f2bs(o[i * 8 + e] * inv);
    *(bf16x8*)(qkv + qoff + i * 8) = t;
  }
}

// ---------------------------------------------------------------------------
// Temporal attention (full 9x9; mask all-False). o over q in-place.
// ---------------------------------------------------------------------------
__global__ __launch_bounds__(256)
void temporal_attn_kernel(ushort_t* __restrict__ qkv) {
  int tid = threadIdx.x;
  int head = tid & 7, hwi = tid >> 3;
  int bi = blockIdx.x;                          // 1152 = 9 * 4 * 32
  int tq = bi >> 7;
  int rest = bi & 127;
  int b = rest >> 5, hwg = rest & 31;
  int hw = (hwg << 5) + hwi;
  long base = (long)(b * TQ_) * 1024 + hw;
  const float scale = 0.17677669529663687f;

  float qf[32];
  long qoff = (base + (long)tq * 1024) * 768 + head * 32;
  #pragma unroll
  for (int i = 0; i < 4; ++i) {
    bf16x8 t = *(const bf16x8*)(qkv + qoff + i * 8);
    #pragma unroll
    for (int e = 0; e < 8; ++e) qf[i * 8 + e] = bs2f((ushort_t)t[e]);
  }
  float s[9];
  #pragma unroll
  for (int tk = 0; tk < 9; ++tk) {
    long ko = (base + (long)tk * 1024) * 768 + 256 + head * 32;
    float d = 0.f;
    #pragma unroll
    for (int i = 0; i < 4; ++i) {
      bf16x8 t = *(const bf16x8*)(qkv + ko + i * 8);
      #pragma unroll
      for (int e = 0; e < 8; ++e) d += qf[i * 8 + e] * bs2f((ushort_t)t[e]);
    }
    s[tk] = d * scale;
  }
  float mx = s[0];
  #pragma unroll
  for (int tk = 1; tk < 9; ++tk) mx = fmaxf(mx, s[tk]);
  float sum = 0.f;
  #pragma unroll
  for (int tk = 0; tk < 9; ++tk) { s[tk] = __expf(s[tk] - mx); sum += s[tk]; }
  float inv = 1.f / sum;

  float o[32];
  #pragma unroll
  for (int i = 0; i < 32; ++i) o[i] = 0.f;
  #pragma unroll
  for (int tk = 0; tk < 9; ++tk) {
    long vo = (base + (long)tk * 1024) * 768 + 512 + head * 32;
    #pragma unroll
    for (int i = 0; i < 4; ++i) {
      bf16x8 t = *(const bf16x8*)(qkv + vo + i * 8);
      #pragma unroll
      for (int e = 0; e < 8; ++e) o[i * 8 + e] += s[tk] * bs2f((ushort_t)t[e]);
    }
  }
  #pragma unroll
  for (int i = 0; i < 4; ++i) {
    bf16x8 t;
    #pragma unroll
    for (int e = 0; e < 8; ++e) t[e] = (short)f2bs(o[i * 8 + e] * inv);
    *(bf16x8*)(qkv + qoff + i * 8) = t;
  }
}

// copy query frame 8 into x (f32); identical linear indices in both buffers
__global__ __launch_bounds__(256)
void copy_frame8_kernel(const float* __restrict__ qy, float* __restrict__ x) {
  long i = (long)blockIdx.x * 256 + threadIdx.x;
  int b = (int)(i >> 18);
  long rem = i & ((1L << 18) - 1);
  long gi = ((long)(b * TQ_ + 8) << 18) + rem;
  x[gi] = qy[gi];
}

// CLS frame mean over spatial: partial sums then broadcast (on f32 x)
__global__ __launch_bounds__(256)
void cls_sum_kernel(const float* __restrict__ x, float* __restrict__ partial) {
  int b = blockIdx.x >> 5, ch = blockIdx.x & 31;
  int d = threadIdx.x;
  long base = ((long)(b * TQ_) * 1024 + ch * 32) * 256 + d;
  float s = 0.f;
  for (int r = 0; r < 32; ++r) s += x[base + (long)r * 256];
  partial[(long)blockIdx.x * 256 + d] = s;
}

__global__ __launch_bounds__(256)
void cls_bcast_kernel(float* __restrict__ x, const float* __restrict__ partial) {
  int b = blockIdx.x >> 3, seg = blockIdx.x & 7;
  int d = threadIdx.x;
  float s = 0.f;
  for (int j = 0; j < 32; ++j) s += partial[(long)(b * 32 + j) * 256 + d];
  s *= (1.f / 1024.f);
  long base = ((long)(b * TQ_) * 1024 + seg * 128) * 256 + d;
  for (int r = 0; r < 128; ++r) x[base + (long)r * 256] = s;
}

// ---------------------------------------------------------------------------
extern "C" void kernel_launch(void* const* d_in, const int* in_sizes, int n_in,
                              void* d_out, int out_size, void* d_ws, size_t ws_size,
                              hipStream_t stream) {
  (void)in_sizes; (void)n_in; (void)out_size; (void)ws_size;
  const float* query = (const float*)d_in[0];
  const float* sln_g = (const float*)d_in[3];
  const float* sln_b = (const float*)d_in[4];
  const float* s_wq  = (const float*)d_in[5];
  const float* s_bq  = (const float*)d_in[6];
  const float* s_wk  = (const float*)d_in[7];
  const float* s_bk  = (const float*)d_in[8];
  const float* s_wv  = (const float*)d_in[9];
  const float* s_bv  = (const float*)d_in[10];
  const float* s_wo  = (const float*)d_in[11];
  const float* s_bo  = (const float*)d_in[12];
  const float* tln_g = (const float*)d_in[13];
  const float* tln_b = (const float*)d_in[14];
  const float* t_wq  = (const float*)d_in[15];
  const float* t_bq  = (const float*)d_in[16];
  const float* t_wk  = (const float*)d_in[17];
  const float* t_bk  = (const float*)d_in[18];
  const float* t_wv  = (const float*)d_in[19];
  const float* t_bv  = (const float*)d_in[20];
  const float* t_wo  = (const float*)d_in[21];
  const float* t_bo  = (const float*)d_in[22];
  const float* mln_g = (const float*)d_in[23];
  const float* mln_b = (const float*)d_in[24];
  const float* w1    = (const float*)d_in[25];
  const float* b1    = (const float*)d_in[26];
  const float* w2    = (const float*)d_in[27];
  const float* b2    = (const float*)d_in[28];
  float* out = (float*)d_out;

  // ---- workspace (~115.4 MB) ----
  const long RB = 36864L * 256;
  ushort_t* XA  = (ushort_t*)d_ws;          // RB bf16
  ushort_t* QKV = XA + RB;                  // 3*RB bf16, rows of 768
  float*    P4  = (float*)(QKV + 3 * RB);   // RB f32 (free during MLP)
  ushort_t* wt  = (ushort_t*)(P4 + RB);     // 2 MB packed weights
  float* bias2  = (float*)(wt + 1048576);   // 2x768 f32
  float* clsp   = bias2 + 1536;             // 128*256 f32
  // MLP hidden: 36864x1024 bf16 = 75.5 MB, spans QKV (56.6) + P4 (first half)
  ushort_t* hid = QKV;

  ushort_t* pk_sqkv = wt;                   // packed [768][256]
  ushort_t* pk_tqkv = wt + 196608;          // packed [768][256]
  ushort_t* pk_swo  = wt + 393216;          // packed [256][256]
  ushort_t* pk_two  = wt + 458752;          // packed [256][256]
  ushort_t* pk_w1   = wt + 524288;          // packed [1024][256]
  ushort_t* pk_w2   = wt + 786432;          // packed [256][1024]

  // ---- weight / bias prep (one pack dispatch) ----
  TPA tp;
  tp.s[0] = s_wq; tp.d[0] = pk_sqkv;          tp.K[0] = 256;  tp.N[0] = 256;  tp.pm[0] = 1;
  tp.s[1] = s_wk; tp.d[1] = pk_sqkv + 65536;  tp.K[1] = 256;  tp.N[1] = 256;  tp.pm[1] = 1;
  tp.s[2] = s_wv; tp.d[2] = pk_sqkv + 131072; tp.K[2] = 256;  tp.N[2] = 256;  tp.pm[2] = 0;
  tp.s[3] = t_wq; tp.d[3] = pk_tqkv;          tp.K[3] = 256;  tp.N[3] = 256;  tp.pm[3] = 1;
  tp.s[4] = t_wk; tp.d[4] = pk_tqkv + 65536;  tp.K[4] = 256;  tp.N[4] = 256;  tp.pm[4] = 1;
  tp.s[5] = t_wv; tp.d[5] = pk_tqkv + 131072; tp.K[5] = 256;  tp.N[5] = 256;  tp.pm[5] = 0;
  tp.s[6] = s_wo; tp.d[6] = pk_swo;           tp.K[6] = 256;  tp.N[6] = 256;  tp.pm[6] = 0;
  tp.s[7] = t_wo; tp.d[7] = pk_two;           tp.K[7] = 256;  tp.N[7] = 256;  tp.pm[7] = 0;
  tp.s[8] = w1;   tp.d[8] = pk_w1;            tp.K[8] = 256;  tp.N[8] = 1024; tp.pm[8] = 0;
  tp.s[9] = w2;   tp.d[9] = pk_w2;            tp.K[9] = 1024; tp.N[9] = 256;  tp.pm[9] = 0;
  pack_all_kernel<<<dim3(32, 32, 10), 256, 0, stream>>>(tp);
  BC6 bc;
  bc.b[0] = s_bq; bc.b[1] = s_bk; bc.b[2] = s_bv;
  bc.b[3] = t_bq; bc.b[4] = t_bk; bc.b[5] = t_bv;
  bias_concat_kernel<<<2, 768, 0, stream>>>(bc, bias2);

  // grid = (M/128)*(N/64) blocks, XCD-group-swizzled inside; NBq = N/256
  #define WGEMM(KV, Ap, ldav, Wp, bi, rs, CF, CB, M, N, rm, om, ac, rp)     \
    wgemm_kernel<KV><<<dim3(((M) / 128) * ((N) / 64)), 256, 0, stream>>>(   \
        Ap, ldav, Wp, bi, rs, CF, CB, N, (N) / 256, rm, om, ac, rp)

  // ---- spatial windowed attention (frames 0..7), M=32768 ----
  ln_norm_kernel<<<8192, 256, 0, stream>>>(query, 1, sln_g, sln_b, XA);
  WGEMM(256, XA, 256, pk_sqkv, bias2, nullptr, nullptr, QKV,
        32768, 768, 0, 2, 0, 0);
  spatial_attn_kernel<<<1024, 256, 0, stream>>>(QKV);
  WGEMM(256, QKV, 768, pk_swo, s_bo, query, P4, nullptr,
        32768, 256, 2, 1, 0, 0);
  copy_frame8_kernel<<<4096, 256, 0, stream>>>(query, P4);

  // ---- temporal RoPE attention, M=36864 ----
  ln_norm_kernel<<<9216, 256, 0, stream>>>(P4, 0, tln_g, tln_b, XA);
  WGEMM(256, XA, 256, pk_tqkv, bias2 + 768, nullptr, nullptr, QKV,
        36864, 768, 0, 2, 0, 1);
  temporal_attn_kernel<<<1152, 256, 0, stream>>>(QKV);
  WGEMM(256, QKV, 768, pk_two, t_bo, P4, out, nullptr,
        36864, 256, 1, 0, 0, 0);

  // ---- CLS frame spatial mean + broadcast (on out = x2) ----
  cls_sum_kernel<<<128, 256, 0, stream>>>(out, clsp);
  cls_bcast_kernel<<<32, 256, 0, stream>>>(out, clsp);

  // ---- MLP, full-M (hid spans QKV+P4) ----
  ln_norm_kernel<<<9216, 256, 0, stream>>>(out, 0, mln_g, mln_b, XA);
  WGEMM(256, XA, 256, pk_w1, b1, nullptr, nullptr, hid,
        36864, 1024, 0, 2, 1, 0);
  WGEMM(1024, hid, 1024, pk_w2, b2, out, out, nullptr,
        36864, 256, 1, 0, 0, 0);
  #undef WGEMM
}

// Round 4
// 562.894 us; speedup vs baseline: 1.4340x; 1.0919x over previous
//
#include <hip/hip_runtime.h>
#include <math.h>

#define TQ_  9

typedef unsigned int   u32;
typedef unsigned short ushort_t;
typedef short bf16x8 __attribute__((ext_vector_type(8)));
typedef float f32x4  __attribute__((ext_vector_type(4)));

__device__ __forceinline__ float bs2f(ushort_t s) {
  return __uint_as_float(((u32)s) << 16);
}
__device__ __forceinline__ ushort_t f2bs(float x) {   // round-to-nearest-even
  u32 u = __float_as_uint(x);
  u32 r = (u + 0x7FFFu + ((u >> 16) & 1u)) >> 16;
  return (ushort_t)r;
}

// ---------------------------------------------------------------------------
// Weight PACK: W f32 [K][N] -> MFMA-B-frag-linear bf16.
// Frag group G = (j*(K/32) + kk)*64 + q*16 + ln holds 8 bf16:
//   element e: out-col n = j*16+ln, k = kk*32 + q*8 + e.
// pm=1 (Q/K weights): out-columns permuted within each 32-col head so RoPE
// pairs (d, d+16) sit at lanes ln, ln^8 of one 16-col chunk:
//   source col local = (ln&7) + 8*(j&1) + 16*(ln>>3).
// Q·K dot products are invariant to this common permutation.
// ---------------------------------------------------------------------------
struct TPA { const float* s[10]; ushort_t* d[10]; int K[10]; int N[10]; int pm[10]; };

__global__ __launch_bounds__(256)
void pack_all_kernel(TPA p) {
  int z = blockIdx.z;
  int K = p.K[z], N = p.N[z];
  int bn = blockIdx.x << 5, bk = blockIdx.y << 5;
  if (bn >= N || bk >= K) return;
  const float* W = p.s[z];
  ushort_t* pk = p.d[z];
  int pm = p.pm[z];
  __shared__ float t[32][33];                 // [k_local][n_local]
  int tid = threadIdx.x;
  int tx = tid & 31, ty = tid >> 5;
  #pragma unroll
  for (int r = 0; r < 4; ++r)
    t[ty + (r << 3)][tx] = W[(long)(bk + ty + (r << 3)) * N + bn + tx];
  __syncthreads();
  if (tid < 128) {
    int jl = tid >> 6, q = (tid >> 4) & 3, ln = tid & 15;
    int j = (bn >> 4) + jl, kk = bk >> 5;
    int colsrc = pm ? ((ln & 7) + (jl << 3) + ((ln & 8) << 1))
                    : ((jl << 4) + ln);
    long G = (((long)j * (K >> 5) + kk) << 6) + (q << 4) + ln;
    bf16x8 ov;
    #pragma unroll
    for (int e = 0; e < 8; ++e)
      ov[e] = (short)f2bs(t[(q << 3) + e][colsrc]);
    *(bf16x8*)(pk + (G << 3)) = ov;
  }
}

// concat 3 biases x 2 stages into f32 [2][768]; Q/K parts permuted to match
struct BC6 { const float* b[6]; };
__global__ __launch_bounds__(768)
void bias_concat_kernel(BC6 p, float* __restrict__ dst) {
  int z = blockIdx.x, n = threadIdx.x;
  int w = n >> 8, q = n & 255;
  int psrc = q;
  if (w < 2)
    psrc = (q & 0xE0) | (q & 7) | (((q >> 4) & 1) << 3) | (((q >> 3) & 1) << 4);
  dst[z * 768 + n] = p.b[z * 3 + w][psrc];
}

// ---------------------------------------------------------------------------
// LayerNorm materialize: one wave per row (4 rows/block), float4 loads.
// ---------------------------------------------------------------------------
__global__ __launch_bounds__(256)
void ln_norm_kernel(const float* __restrict__ src, int spatial,
                    const float* __restrict__ g, const float* __restrict__ b,
                    ushort_t* __restrict__ dst) {
  int row = blockIdx.x * 4 + (threadIdx.x >> 6);
  int lane = threadIdx.x & 63;
  long srow = row;
  if (spatial) {
    int bq = row >> 13, r = row & 8191;
    srow = ((long)(bq * TQ_ + (r >> 10)) << 10) + (r & 1023);
  }
  float4 v = ((const float4*)(src + srow * 256))[lane];
  float s  = v.x + v.y + v.z + v.w;
  float s2 = v.x * v.x + v.y * v.y + v.z * v.z + v.w * v.w;
  #pragma unroll
  for (int m = 32; m; m >>= 1) {
    s  += __shfl_xor(s,  m, 64);
    s2 += __shfl_xor(s2, m, 64);
  }
  float mean = s * (1.f / 256.f);
  float rstd = rsqrtf(s2 * (1.f / 256.f) - mean * mean + 1e-5f);
  float4 gv = ((const float4*)g)[lane];
  float4 bv = ((const float4*)b)[lane];
  ushort_t o[4];
  o[0] = f2bs((v.x - mean) * rstd * gv.x + bv.x);
  o[1] = f2bs((v.y - mean) * rstd * gv.y + bv.y);
  o[2] = f2bs((v.z - mean) * rstd * gv.z + bv.z);
  o[3] = f2bs((v.w - mean) * rstd * gv.w + bv.w);
  u32 lo = (u32)o[0] | ((u32)o[1] << 16);
  u32 hi = (u32)o[2] | ((u32)o[3] << 16);
  uint2 pk; pk.x = lo; pk.y = hi;
  *(uint2*)(dst + (long)row * 256 + lane * 4) = pk;
}

// ---------------------------------------------------------------------------
// Barrier-free register-streaming GEMM (no LDS at all).
//   C[M,N] = A[M,K](lda, bf16) @ W^T + bias (+rope)(+gelu)(+resid)
// Each WAVE is an independent 32(M) x 64(N) tile; block = 4 waves stacked in
// M (tile 128x64). 1-D grid, XCD-grouping swizzle (groups of 32 ids = 8
// m-panels x 4 n-chunks on one XCD -> A panel HBM-fetched once, L2-served).
// B is read DIRECTLY from the packed frag-linear weights (1KB fully-coalesced
// load per frag; W is 128-512KB -> L2-resident). A frags are 16 rows x 64B
// contiguous slices (L1/L2 friendly). Register pipeline: A 4 steps deep,
// B 2 steps deep, STATIC ring indices via full unroll (rule #20).
// K-loop body is COMPUTE-then-PREFETCH: the prefetch for step kk+AD refills
// the slot consumed by step kk's MFMA (same slot index mod AD). C order
// guarantees the MFMA reads the OLD value; the compiler renames registers
// and hoists the load issue, keeping AD steps in flight.  (Round-3 bug:
// prefetch-before-compute made the MFMA read the NEW k-slice -> wrong sums.)
// No barriers, no LDS: occupancy is VGPR-limited only and every wave makes
// independent progress; latency hidden by TLP.
// resid_mode: 0 none, 1 f32 contiguous [m][256], 2 f32 query spatial-mapped
// out_mode:   0 f32 [m][N], 1 f32 spatial->9-frame map [orow][256], 2 bf16
// rope: permuted-pair RoPE via __shfl_xor(8) on chunks jglb<32.
// ---------------------------------------------------------------------------
template<int K>
__global__ __launch_bounds__(256, 4)
void wgemm_kernel(const ushort_t* __restrict__ A, int lda,
                  const ushort_t* __restrict__ packW,
                  const float* __restrict__ bias, const float* __restrict__ resid,
                  float* __restrict__ Cf, ushort_t* __restrict__ Cb,
                  int N, int NBq, int resid_mode, int out_mode, int act, int rope) {
  constexpr int K32 = K / 32;
  constexpr int AD = (K32 >= 4) ? 4 : K32;    // A prefetch depth (reg ring)
  constexpr int BD = 2;                       // B prefetch depth

  int tid = threadIdx.x;
  int wv = tid >> 6, lane = tid & 63;
  int ln = lane & 15, q4 = lane >> 4;

  // XCD-grouping decode
  int gid = blockIdx.x;
  int g = gid >> 5, r = gid & 31;
  int nq = (r >> 3) + ((g % NBq) << 2);
  int mb = ((g / NBq) << 3) + (r & 7);
  int m0 = mb << 7, n0 = nq << 6;

  const ushort_t* Ap = A + (long)(m0 + (wv << 5) + ln) * lda + (q4 << 3);
  long a16 = (long)lda << 4;                  // +16 rows
  const ushort_t* Bp = packW + (((long)(nq << 2) * K32) << 9) + (lane << 3);
  // chunk j (0..3), step kk lives at Bp + ((j*K32 + kk) << 9)

  bf16x8 ar[AD][2];
  bf16x8 br[BD][4];
  #pragma unroll
  for (int d = 0; d < AD; ++d) {
    ar[d][0] = *(const bf16x8*)(Ap + d * 32);
    ar[d][1] = *(const bf16x8*)(Ap + a16 + d * 32);
  }
  #pragma unroll
  for (int d = 0; d < BD; ++d)
    #pragma unroll
    for (int j = 0; j < 4; ++j)
      br[d][j] = *(const bf16x8*)(Bp + (((long)j * K32 + d) << 9));

  f32x4 acc[2][4];
  #pragma unroll
  for (int i = 0; i < 2; ++i)
    #pragma unroll
    for (int j = 0; j < 4; ++j) acc[i][j] = 0.f;

  #pragma unroll
  for (int kk = 0; kk < K32; ++kk) {          // fully unrolled: static indices
    // ---- compute step kk (reads OLD slot contents) ----
    #pragma unroll
    for (int i = 0; i < 2; ++i)
      #pragma unroll
      for (int j = 0; j < 4; ++j)
        acc[i][j] = __builtin_amdgcn_mfma_f32_16x16x32_bf16(
            ar[kk % AD][i], br[kk % BD][j], acc[i][j], 0, 0, 0);
    // ---- refill the just-consumed slots with step kk+AD / kk+BD ----
    if (kk + AD < K32) {
      ar[kk % AD][0] = *(const bf16x8*)(Ap + (kk + AD) * 32);
      ar[kk % AD][1] = *(const bf16x8*)(Ap + a16 + (kk + AD) * 32);
    }
    if (kk + BD < K32) {
      #pragma unroll
      for (int j = 0; j < 4; ++j)
        br[kk % BD][j] = *(const bf16x8*)(Bp + (((long)j * K32 + kk + BD) << 9));
    }
  }

  // ---- epilogue ----
  float bv[4];
  #pragma unroll
  for (int j = 0; j < 4; ++j) bv[j] = bias[n0 + (j << 4) + ln];

  // RoPE cos/sin for both chunk parities (t uniform: 128-row tile within one
  // 1024-row frame block)
  float c0 = 1.f, ss0 = 0.f, c1 = 1.f, ss1 = 0.f;
  if (rope) {
    int t = (m0 >> 10) % TQ_;
    float d0 = (float)(ln & 7);
    float a0 = (float)t * exp2f(d0 * -0.8304820237218406f);
    float a1 = (float)t * exp2f((d0 + 8.f) * -0.8304820237218406f);
    float s0 = sinf(a0), s1 = sinf(a1);
    c0 = cosf(a0); c1 = cosf(a1);
    ss0 = (ln & 8) ? s0 : -s0;
    ss1 = (ln & 8) ? s1 : -s1;
  }

  #pragma unroll
  for (int i = 0; i < 2; ++i) {
    int mbase = m0 + (wv << 5) + (i << 4) + (q4 << 2);
    float v[4][4];
    #pragma unroll
    for (int j = 0; j < 4; ++j)
      #pragma unroll
      for (int r2 = 0; r2 < 4; ++r2) v[j][r2] = acc[i][j][r2] + bv[j];
    if (rope) {
      #pragma unroll
      for (int j = 0; j < 4; ++j) {
        int jglb = (nq << 2) + j;
        if (jglb < 32) {                      // Q,K region (first 512 cols)
          float cc = (jglb & 1) ? c1 : c0;
          float ss = (jglb & 1) ? ss1 : ss0;
          #pragma unroll
          for (int r2 = 0; r2 < 4; ++r2) {
            float other = __shfl_xor(v[j][r2], 8, 64);
            v[j][r2] = v[j][r2] * cc + other * ss;
          }
        }
      }
    }
    if (act) {
      #pragma unroll
      for (int j = 0; j < 4; ++j)
        #pragma unroll
        for (int r2 = 0; r2 < 4; ++r2) {
          float x = v[j][r2];
          v[j][r2] = 0.5f * x * (1.f + erff(x * 0.70710678118654752f));
        }
    }
    #pragma unroll
    for (int r2 = 0; r2 < 4; ++r2) {
      int m = mbase + r2;
      long orow = m;
      if (out_mode == 1 || resid_mode == 2) {
        int bq = m >> 13, rr = m & 8191;
        orow = ((long)(bq * TQ_ + (rr >> 10)) << 10) + (rr & 1023);
      }
      #pragma unroll
      for (int j = 0; j < 4; ++j) {
        int n = n0 + (j << 4) + ln;
        float x = v[j][r2];
        if (resid_mode == 1)      x += resid[(long)m * 256 + n];
        else if (resid_mode == 2) x += resid[orow * 256 + n];
        if (out_mode == 2)      Cb[(long)m * N + n] = f2bs(x);
        else if (out_mode == 1) Cf[orow * 256 + n] = x;
        else                    Cf[(long)m * N + n] = x;
      }
    }
  }
}

// ---------------------------------------------------------------------------
// Spatial 3x3 windowed attention on packed QKV [m][768] bf16. One thread per
// (pixel, head), head-fast. o over q in-place. (Q/K head-dim permutation is
// common to q and k -> dot products unchanged.)
// ---------------------------------------------------------------------------
__global__ __launch_bounds__(256)
void spatial_attn_kernel(ushort_t* __restrict__ qkv) {
  int gid = blockIdx.x * 256 + threadIdx.x;   // 262144
  int head = gid & 7, pixel = gid >> 3;
  int pix = pixel & 1023, bt = pixel >> 10;
  int y = pix >> 5, x = pix & 31;
  long rb = (long)bt << 10;
  const float scale = 0.17677669529663687f;   // 1/sqrt(32)

  float qf[32];
  long qoff = (long)pixel * 768 + head * 32;
  #pragma unroll
  for (int i = 0; i < 4; ++i) {
    bf16x8 t = *(const bf16x8*)(qkv + qoff + i * 8);
    #pragma unroll
    for (int e = 0; e < 8; ++e) qf[i * 8 + e] = bs2f((ushort_t)t[e]);
  }

  float s[9];
  bool val[9];
  #pragma unroll
  for (int n = 0; n < 9; ++n) {
    int yy = y + n / 3 - 1, xx = x + n % 3 - 1;
    bool ok = ((unsigned)yy < 32u) & ((unsigned)xx < 32u);
    val[n] = ok;
    float d = 0.f;
    if (ok) {
      long ko = (rb + (yy << 5) + xx) * 768 + 256 + head * 32;
      #pragma unroll
      for (int i = 0; i < 4; ++i) {
        bf16x8 t = *(const bf16x8*)(qkv + ko + i * 8);
        #pragma unroll
        for (int e = 0; e < 8; ++e) d += qf[i * 8 + e] * bs2f((ushort_t)t[e]);
      }
    }
    s[n] = d * scale;
  }
  float mx = -1e30f;
  #pragma unroll
  for (int n = 0; n < 9; ++n) if (val[n]) mx = fmaxf(mx, s[n]);
  float sum = 0.f;
  #pragma unroll
  for (int n = 0; n < 9; ++n) { s[n] = val[n] ? __expf(s[n] - mx) : 0.f; sum += s[n]; }
  float inv = 1.f / sum;

  float o[32];
  #pragma unroll
  for (int i = 0; i < 32; ++i) o[i] = 0.f;
  #pragma unroll
  for (int n = 0; n < 9; ++n) {
    if (val[n]) {
      int yy = y + n / 3 - 1, xx = x + n % 3 - 1;
      long vo = (rb + (yy << 5) + xx) * 768 + 512 + head * 32;
      #pragma unroll
      for (int i = 0; i < 4; ++i) {
        bf16x8 t = *(const bf16x8*)(qkv + vo + i * 8);
        #pragma unroll
        for (int e = 0; e < 8; ++e) o[i * 8 + e] += s[n] * bs2f((ushort_t)t[e]);
      }
    }
  }
  #pragma unroll
  for (int i = 0; i < 4; ++i) {
    bf16x8 t;
    #pragma unroll
    for (int e = 0; e < 8; ++e) t[e] = (short)f2bs(o[i * 8 + e] * inv);
    *(bf16x8*)(qkv + qoff + i * 8) = t;
  }
}

// ---------------------------------------------------------------------------
// Temporal attention (full 9x9; mask all-False). o over q in-place.
// ---------------------------------------------------------------------------
__global__ __launch_bounds__(256)
void temporal_attn_kernel(ushort_t* __restrict__ qkv) {
  int tid = threadIdx.x;
  int head = tid & 7, hwi = tid >> 3;
  int bi = blockIdx.x;                          // 1152 = 9 * 4 * 32
  int tq = bi >> 7;
  int rest = bi & 127;
  int b = rest >> 5, hwg = rest & 31;
  int hw = (hwg << 5) + hwi;
  long base = (long)(b * TQ_) * 1024 + hw;
  const float scale = 0.17677669529663687f;

  float qf[32];
  long qoff = (base + (long)tq * 1024) * 768 + head * 32;
  #pragma unroll
  for (int i = 0; i < 4; ++i) {
    bf16x8 t = *(const bf16x8*)(qkv + qoff + i * 8);
    #pragma unroll
    for (int e = 0; e < 8; ++e) qf[i * 8 + e] = bs2f((ushort_t)t[e]);
  }
  float s[9];
  #pragma unroll
  for (int tk = 0; tk < 9; ++tk) {
    long ko = (base + (long)tk * 1024) * 768 + 256 + head * 32;
    float d = 0.f;
    #pragma unroll
    for (int i = 0; i < 4; ++i) {
      bf16x8 t = *(const bf16x8*)(qkv + ko + i * 8);
      #pragma unroll
      for (int e = 0; e < 8; ++e) d += qf[i * 8 + e] * bs2f((ushort_t)t[e]);
    }
    s[tk] = d * scale;
  }
  float mx = s[0];
  #pragma unroll
  for (int tk = 1; tk < 9; ++tk) mx = fmaxf(mx, s[tk]);
  float sum = 0.f;
  #pragma unroll
  for (int tk = 0; tk < 9; ++tk) { s[tk] = __expf(s[tk] - mx); sum += s[tk]; }
  float inv = 1.f / sum;

  float o[32];
  #pragma unroll
  for (int i = 0; i < 32; ++i) o[i] = 0.f;
  #pragma unroll
  for (int tk = 0; tk < 9; ++tk) {
    long vo = (base + (long)tk * 1024) * 768 + 512 + head * 32;
    #pragma unroll
    for (int i = 0; i < 4; ++i) {
      bf16x8 t = *(const bf16x8*)(qkv + vo + i * 8);
      #pragma unroll
      for (int e = 0; e < 8; ++e) o[i * 8 + e] += s[tk] * bs2f((ushort_t)t[e]);
    }
  }
  #pragma unroll
  for (int i = 0; i < 4; ++i) {
    bf16x8 t;
    #pragma unroll
    for (int e = 0; e < 8; ++e) t[e] = (short)f2bs(o[i * 8 + e] * inv);
    *(bf16x8*)(qkv + qoff + i * 8) = t;
  }
}

// copy query frame 8 into x (f32); identical linear indices in both buffers
__global__ __launch_bounds__(256)
void copy_frame8_kernel(const float* __restrict__ qy, float* __restrict__ x) {
  long i = (long)blockIdx.x * 256 + threadIdx.x;
  int b = (int)(i >> 18);
  long rem = i & ((1L << 18) - 1);
  long gi = ((long)(b * TQ_ + 8) << 18) + rem;
  x[gi] = qy[gi];
}

// CLS frame mean over spatial: partial sums then broadcast (on f32 x)
__global__ __launch_bounds__(256)
void cls_sum_kernel(const float* __restrict__ x, float* __restrict__ partial) {
  int b = blockIdx.x >> 5, ch = blockIdx.x & 31;
  int d = threadIdx.x;
  long base = ((long)(b * TQ_) * 1024 + ch * 32) * 256 + d;
  float s = 0.f;
  for (int r = 0; r < 32; ++r) s += x[base + (long)r * 256];
  partial[(long)blockIdx.x * 256 + d] = s;
}

__global__ __launch_bounds__(256)
void cls_bcast_kernel(float* __restrict__ x, const float* __restrict__ partial) {
  int b = blockIdx.x >> 3, seg = blockIdx.x & 7;
  int d = threadIdx.x;
  float s = 0.f;
  for (int j = 0; j < 32; ++j) s += partial[(long)(b * 32 + j) * 256 + d];
  s *= (1.f / 1024.f);
  long base = ((long)(b * TQ_) * 1024 + seg * 128) * 256 + d;
  for (int r = 0; r < 128; ++r) x[base + (long)r * 256] = s;
}

// ---------------------------------------------------------------------------
extern "C" void kernel_launch(void* const* d_in, const int* in_sizes, int n_in,
                              void* d_out, int out_size, void* d_ws, size_t ws_size,
                              hipStream_t stream) {
  (void)in_sizes; (void)n_in; (void)out_size; (void)ws_size;
  const float* query = (const float*)d_in[0];
  const float* sln_g = (const float*)d_in[3];
  const float* sln_b = (const float*)d_in[4];
  const float* s_wq  = (const float*)d_in[5];
  const float* s_bq  = (const float*)d_in[6];
  const float* s_wk  = (const float*)d_in[7];
  const float* s_bk  = (const float*)d_in[8];
  const float* s_wv  = (const float*)d_in[9];
  const float* s_bv  = (const float*)d_in[10];
  const float* s_wo  = (const float*)d_in[11];
  const float* s_bo  = (const float*)d_in[12];
  const float* tln_g = (const float*)d_in[13];
  const float* tln_b = (const float*)d_in[14];
  const float* t_wq  = (const float*)d_in[15];
  const float* t_bq  = (const float*)d_in[16];
  const float* t_wk  = (const float*)d_in[17];
  const float* t_bk  = (const float*)d_in[18];
  const float* t_wv  = (const float*)d_in[19];
  const float* t_bv  = (const float*)d_in[20];
  const float* t_wo  = (const float*)d_in[21];
  const float* t_bo  = (const float*)d_in[22];
  const float* mln_g = (const float*)d_in[23];
  const float* mln_b = (const float*)d_in[24];
  const float* w1    = (const float*)d_in[25];
  const float* b1    = (const float*)d_in[26];
  const float* w2    = (const float*)d_in[27];
  const float* b2    = (const float*)d_in[28];
  float* out = (float*)d_out;

  // ---- workspace (~115.4 MB) ----
  const long RB = 36864L * 256;
  ushort_t* XA  = (ushort_t*)d_ws;          // RB bf16
  ushort_t* QKV = XA + RB;                  // 3*RB bf16, rows of 768
  float*    P4  = (float*)(QKV + 3 * RB);   // RB f32 (free during MLP)
  ushort_t* wt  = (ushort_t*)(P4 + RB);     // 2 MB packed weights
  float* bias2  = (float*)(wt + 1048576);   // 2x768 f32
  float* clsp   = bias2 + 1536;             // 128*256 f32
  // MLP hidden: 36864x1024 bf16 = 75.5 MB, spans QKV (56.6) + P4 (first half)
  ushort_t* hid = QKV;

  ushort_t* pk_sqkv = wt;                   // packed [768][256]
  ushort_t* pk_tqkv = wt + 196608;          // packed [768][256]
  ushort_t* pk_swo  = wt + 393216;          // packed [256][256]
  ushort_t* pk_two  = wt + 458752;          // packed [256][256]
  ushort_t* pk_w1   = wt + 524288;          // packed [1024][256]
  ushort_t* pk_w2   = wt + 786432;          // packed [256][1024]

  // ---- weight / bias prep (one pack dispatch) ----
  TPA tp;
  tp.s[0] = s_wq; tp.d[0] = pk_sqkv;          tp.K[0] = 256;  tp.N[0] = 256;  tp.pm[0] = 1;
  tp.s[1] = s_wk; tp.d[1] = pk_sqkv + 65536;  tp.K[1] = 256;  tp.N[1] = 256;  tp.pm[1] = 1;
  tp.s[2] = s_wv; tp.d[2] = pk_sqkv + 131072; tp.K[2] = 256;  tp.N[2] = 256;  tp.pm[2] = 0;
  tp.s[3] = t_wq; tp.d[3] = pk_tqkv;          tp.K[3] = 256;  tp.N[3] = 256;  tp.pm[3] = 1;
  tp.s[4] = t_wk; tp.d[4] = pk_tqkv + 65536;  tp.K[4] = 256;  tp.N[4] = 256;  tp.pm[4] = 1;
  tp.s[5] = t_wv; tp.d[5] = pk_tqkv + 131072; tp.K[5] = 256;  tp.N[5] = 256;  tp.pm[5] = 0;
  tp.s[6] = s_wo; tp.d[6] = pk_swo;           tp.K[6] = 256;  tp.N[6] = 256;  tp.pm[6] = 0;
  tp.s[7] = t_wo; tp.d[7] = pk_two;           tp.K[7] = 256;  tp.N[7] = 256;  tp.pm[7] = 0;
  tp.s[8] = w1;   tp.d[8] = pk_w1;            tp.K[8] = 256;  tp.N[8] = 1024; tp.pm[8] = 0;
  tp.s[9] = w2;   tp.d[9] = pk_w2;            tp.K[9] = 1024; tp.N[9] = 256;  tp.pm[9] = 0;
  pack_all_kernel<<<dim3(32, 32, 10), 256, 0, stream>>>(tp);
  BC6 bc;
  bc.b[0] = s_bq; bc.b[1] = s_bk; bc.b[2] = s_bv;
  bc.b[3] = t_bq; bc.b[4] = t_bk; bc.b[5] = t_bv;
  bias_concat_kernel<<<2, 768, 0, stream>>>(bc, bias2);

  // grid = (M/128)*(N/64) blocks, XCD-group-swizzled inside; NBq = N/256
  #define WGEMM(KV, Ap, ldav, Wp, bi, rs, CF, CB, M, N, rm, om, ac, rp)     \
    wgemm_kernel<KV><<<dim3(((M) / 128) * ((N) / 64)), 256, 0, stream>>>(   \
        Ap, ldav, Wp, bi, rs, CF, CB, N, (N) / 256, rm, om, ac, rp)

  // ---- spatial windowed attention (frames 0..7), M=32768 ----
  ln_norm_kernel<<<8192, 256, 0, stream>>>(query, 1, sln_g, sln_b, XA);
  WGEMM(256, XA, 256, pk_sqkv, bias2, nullptr, nullptr, QKV,
        32768, 768, 0, 2, 0, 0);
  spatial_attn_kernel<<<1024, 256, 0, stream>>>(QKV);
  WGEMM(256, QKV, 768, pk_swo, s_bo, query, P4, nullptr,
        32768, 256, 2, 1, 0, 0);
  copy_frame8_kernel<<<4096, 256, 0, stream>>>(query, P4);

  // ---- temporal RoPE attention, M=36864 ----
  ln_norm_kernel<<<9216, 256, 0, stream>>>(P4, 0, tln_g, tln_b, XA);
  WGEMM(256, XA, 256, pk_tqkv, bias2 + 768, nullptr, nullptr, QKV,
        36864, 768, 0, 2, 0, 1);
  temporal_attn_kernel<<<1152, 256, 0, stream>>>(QKV);
  WGEMM(256, QKV, 768, pk_two, t_bo, P4, out, nullptr,
        36864, 256, 1, 0, 0, 0);

  // ---- CLS frame spatial mean + broadcast (on out = x2) ----
  cls_sum_kernel<<<128, 256, 0, stream>>>(out, clsp);
  cls_bcast_kernel<<<32, 256, 0, stream>>>(out, clsp);

  // ---- MLP, full-M (hid spans QKV+P4) ----
  ln_norm_kernel<<<9216, 256, 0, stream>>>(out, 0, mln_g, mln_b, XA);
  WGEMM(256, XA, 256, pk_w1, b1, nullptr, nullptr, hid,
        36864, 1024, 0, 2, 1, 0);
  WGEMM(1024, hid, 1024, pk_w2, b2, out, out, nullptr,
        36864, 256, 1, 0, 0, 0);
  #undef WGEMM
}

// Round 5
// 527.143 us; speedup vs baseline: 1.5313x; 1.0678x over previous
//
#include <hip/hip_runtime.h>
#include <math.h>

#define TQ_  9

typedef unsigned int   u32;
typedef unsigned short ushort_t;
typedef short bf16x8 __attribute__((ext_vector_type(8)));
typedef float f32x4  __attribute__((ext_vector_type(4)));

__device__ __forceinline__ float bs2f(ushort_t s) {
  return __uint_as_float(((u32)s) << 16);
}
__device__ __forceinline__ ushort_t f2bs(float x) {   // round-to-nearest-even
  u32 u = __float_as_uint(x);
  u32 r = (u + 0x7FFFu + ((u >> 16) & 1u)) >> 16;
  return (ushort_t)r;
}

// ---------------------------------------------------------------------------
// Weight PACK: W f32 [K][N] -> MFMA-frag-linear bf16 (A-operand layout).
// Frag group G = (j*(K/32) + kk)*64 + q*16 + ln holds 8 bf16:
//   element e: out-col n = j*16+ln, k = kk*32 + q*8 + e.
// pm=1 (Q/K weights): out-columns permuted within each 32-col head so RoPE
// pairs (d, d+16) sit at positions c, c^8 of a 16-col chunk:
//   source col local = (c&7) + 8*(j&1) + 16*(c>>3).
// Q·K dot products are invariant to this common permutation.
// ---------------------------------------------------------------------------
struct TPA { const float* s[10]; ushort_t* d[10]; int K[10]; int N[10]; int pm[10]; };

__global__ __launch_bounds__(256)
void pack_all_kernel(TPA p) {
  int z = blockIdx.z;
  int K = p.K[z], N = p.N[z];
  int bn = blockIdx.x << 5, bk = blockIdx.y << 5;
  if (bn >= N || bk >= K) return;
  const float* W = p.s[z];
  ushort_t* pk = p.d[z];
  int pm = p.pm[z];
  __shared__ float t[32][33];                 // [k_local][n_local]
  int tid = threadIdx.x;
  int tx = tid & 31, ty = tid >> 5;
  #pragma unroll
  for (int r = 0; r < 4; ++r)
    t[ty + (r << 3)][tx] = W[(long)(bk + ty + (r << 3)) * N + bn + tx];
  __syncthreads();
  if (tid < 128) {
    int jl = tid >> 6, q = (tid >> 4) & 3, ln = tid & 15;
    int j = (bn >> 4) + jl, kk = bk >> 5;
    int colsrc = pm ? ((ln & 7) + (jl << 3) + ((ln & 8) << 1))
                    : ((jl << 4) + ln);
    long G = (((long)j * (K >> 5) + kk) << 6) + (q << 4) + ln;
    bf16x8 ov;
    #pragma unroll
    for (int e = 0; e < 8; ++e)
      ov[e] = (short)f2bs(t[(q << 3) + e][colsrc]);
    *(bf16x8*)(pk + (G << 3)) = ov;
  }
}

// concat 3 biases x 2 stages into f32 [2][768]; Q/K parts permuted to match
struct BC6 { const float* b[6]; };
__global__ __launch_bounds__(768)
void bias_concat_kernel(BC6 p, float* __restrict__ dst) {
  int z = blockIdx.x, n = threadIdx.x;
  int w = n >> 8, q = n & 255;
  int psrc = q;
  if (w < 2)
    psrc = (q & 0xE0) | (q & 7) | (((q >> 4) & 1) << 3) | (((q >> 3) & 1) << 4);
  dst[z * 768 + n] = p.b[z * 3 + w][psrc];
}

// ---------------------------------------------------------------------------
// LayerNorm materialize: one wave per row (4 rows/block), float4 loads.
// ---------------------------------------------------------------------------
__global__ __launch_bounds__(256)
void ln_norm_kernel(const float* __restrict__ src, int spatial,
                    const float* __restrict__ g, const float* __restrict__ b,
                    ushort_t* __restrict__ dst) {
  int row = blockIdx.x * 4 + (threadIdx.x >> 6);
  int lane = threadIdx.x & 63;
  long srow = row;
  if (spatial) {
    int bq = row >> 13, r = row & 8191;
    srow = ((long)(bq * TQ_ + (r >> 10)) << 10) + (r & 1023);
  }
  float4 v = ((const float4*)(src + srow * 256))[lane];
  float s  = v.x + v.y + v.z + v.w;
  float s2 = v.x * v.x + v.y * v.y + v.z * v.z + v.w * v.w;
  #pragma unroll
  for (int m = 32; m; m >>= 1) {
    s  += __shfl_xor(s,  m, 64);
    s2 += __shfl_xor(s2, m, 64);
  }
  float mean = s * (1.f / 256.f);
  float rstd = rsqrtf(s2 * (1.f / 256.f) - mean * mean + 1e-5f);
  float4 gv = ((const float4*)g)[lane];
  float4 bv = ((const float4*)b)[lane];
  ushort_t o[4];
  o[0] = f2bs((v.x - mean) * rstd * gv.x + bv.x);
  o[1] = f2bs((v.y - mean) * rstd * gv.y + bv.y);
  o[2] = f2bs((v.z - mean) * rstd * gv.z + bv.z);
  o[3] = f2bs((v.w - mean) * rstd * gv.w + bv.w);
  u32 lo = (u32)o[0] | ((u32)o[1] << 16);
  u32 hi = (u32)o[2] | ((u32)o[3] << 16);
  uint2 pk; pk.x = lo; pk.y = hi;
  *(uint2*)(dst + (long)row * 256 + lane * 4) = pk;
}

// ---------------------------------------------------------------------------
// Barrier-free register-streaming GEMM (no LDS), SWAPPED operand order:
//   D = W_frag (A-op, n-rows) x X_frag (B-op, m-cols)  ->  D[n][m]
// C/D layout (col=lane&15, row=(lane>>4)*4+reg) then gives each lane 4
// CONSECUTIVE n for ONE row m -> float4 stores / float4 resid loads /
// float4 bias / uint2 bf16 stores. Epilogue VMEM ops are cut 4x vs the
// scalar-scatter epilogue that was invariant across rounds 0-4 (~90us).
// A/B fragment layouts are symmetric for 16x16x32, so the packed weights
// and the X row loads are unchanged.
// K-loop: compute-then-prefetch register rings (A 4-deep, B 2-deep, static
// indices) with __builtin_amdgcn_sched_barrier(0) at each body end so the
// scheduler cannot sink the prefetch loads into later iterations (round-4
// counters: VGPR=56 proved the rings were collapsed to depth ~1).
// Each wave: independent 32(M) x 64(N) tile; block = 4 waves stacked in M.
// 1-D grid, XCD-grouping swizzle (32 ids = 8 m-panels x 4 n-chunks per XCD).
// resid_mode: 0 none, 1 f32 contiguous [m][256], 2 f32 query spatial-mapped
// out_mode:   0 f32 [m][N], 1 f32 spatial->9-frame map [orow][256], 2 bf16
// rope: permuted-pair RoPE via __shfl_xor(32) on chunks jglb<32.
// ---------------------------------------------------------------------------
template<int K>
__global__ __launch_bounds__(256, 4)
void wgemm_kernel(const ushort_t* __restrict__ A, int lda,
                  const ushort_t* __restrict__ packW,
                  const float* __restrict__ bias, const float* __restrict__ resid,
                  float* __restrict__ Cf, ushort_t* __restrict__ Cb,
                  int N, int NBq, int resid_mode, int out_mode, int act, int rope) {
  constexpr int K32 = K / 32;
  constexpr int AD = (K32 >= 4) ? 4 : K32;    // X prefetch depth (reg ring)
  constexpr int BD = 2;                       // W prefetch depth

  int tid = threadIdx.x;
  int wv = tid >> 6, lane = tid & 63;
  int ln = lane & 15, q4 = lane >> 4;

  // XCD-grouping decode
  int gid = blockIdx.x;
  int g = gid >> 5, r = gid & 31;
  int nq = (r >> 3) + ((g % NBq) << 2);
  int mb = ((g / NBq) << 3) + (r & 7);
  int m0 = mb << 7, n0 = nq << 6;

  const ushort_t* Ap = A + (long)(m0 + (wv << 5) + ln) * lda + (q4 << 3);
  long a16 = (long)lda << 4;                  // +16 rows
  const ushort_t* Bp = packW + (((long)(nq << 2) * K32) << 9) + (lane << 3);
  // chunk j (0..3), step kk lives at Bp + ((j*K32 + kk) << 9)

  bf16x8 xr[AD][2];                           // X fragments (B-operand)
  bf16x8 wr[BD][4];                           // W fragments (A-operand)
  #pragma unroll
  for (int d = 0; d < BD; ++d)
    #pragma unroll
    for (int j = 0; j < 4; ++j)
      wr[d][j] = *(const bf16x8*)(Bp + (((long)j * K32 + d) << 9));
  #pragma unroll
  for (int d = 0; d < AD; ++d) {
    xr[d][0] = *(const bf16x8*)(Ap + d * 32);
    xr[d][1] = *(const bf16x8*)(Ap + a16 + d * 32);
  }

  f32x4 acc[2][4];
  #pragma unroll
  for (int i = 0; i < 2; ++i)
    #pragma unroll
    for (int j = 0; j < 4; ++j) acc[i][j] = 0.f;

  #pragma unroll
  for (int kk = 0; kk < K32; ++kk) {          // fully unrolled: static indices
    // ---- compute step kk (reads OLD slot contents) ----
    #pragma unroll
    for (int i = 0; i < 2; ++i)
      #pragma unroll
      for (int j = 0; j < 4; ++j)
        acc[i][j] = __builtin_amdgcn_mfma_f32_16x16x32_bf16(
            wr[kk % BD][j], xr[kk % AD][i], acc[i][j], 0, 0, 0);
    // ---- refill the just-consumed slots with step kk+AD / kk+BD ----
    if (kk + AD < K32) {
      xr[kk % AD][0] = *(const bf16x8*)(Ap + (kk + AD) * 32);
      xr[kk % AD][1] = *(const bf16x8*)(Ap + a16 + (kk + AD) * 32);
    }
    if (kk + BD < K32) {
      #pragma unroll
      for (int j = 0; j < 4; ++j)
        wr[kk % BD][j] = *(const bf16x8*)(Bp + (((long)j * K32 + kk + BD) << 9));
    }
    __builtin_amdgcn_sched_barrier(0);        // pin prefetch distance
  }

  // ---- epilogue (all lane-contiguous: float4 / uint2) ----
  float4 bj[4];
  #pragma unroll
  for (int j = 0; j < 4; ++j)
    bj[j] = *(const float4*)(bias + n0 + (j << 4) + (q4 << 2));

  // RoPE tables per (chunk parity p, reg r2); partner lane = lane^32.
  float cs_c[2][4], cs_s[2][4];
  if (rope) {
    int t = (m0 >> 10) % TQ_;
    #pragma unroll
    for (int p = 0; p < 2; ++p)
      #pragma unroll
      for (int r2 = 0; r2 < 4; ++r2) {
        float d = (float)(((q4 & 1) << 2) + r2 + (p << 3));
        float ang = (float)t * exp2f(d * -0.8304820237218406f);
        cs_c[p][r2] = cosf(ang);
        float s = sinf(ang);
        cs_s[p][r2] = (q4 & 2) ? s : -s;      // x1 lanes: -s, x2 lanes: +s
      }
  }

  #pragma unroll
  for (int i = 0; i < 2; ++i) {
    int m = m0 + (wv << 5) + (i << 4) + ln;   // per-lane output row
    long orow = m;
    if (out_mode == 1 || resid_mode == 2) {
      int bq = m >> 13, rr = m & 8191;
      orow = ((long)(bq * TQ_ + (rr >> 10)) << 10) + (rr & 1023);
    }
    #pragma unroll
    for (int j = 0; j < 4; ++j) {
      int n = n0 + (j << 4) + (q4 << 2);      // 4 consecutive cols per lane
      float v[4];
      #pragma unroll
      for (int r2 = 0; r2 < 4; ++r2) v[r2] = acc[i][j][r2] + bj[j][r2];
      if (rope && ((nq << 2) + j) < 32) {     // Q,K region (first 512 cols)
        #pragma unroll
        for (int r2 = 0; r2 < 4; ++r2) {
          float other = __shfl_xor(v[r2], 32, 64);
          v[r2] = v[r2] * cs_c[j & 1][r2] + other * cs_s[j & 1][r2];
        }
      }
      if (act) {
        #pragma unroll
        for (int r2 = 0; r2 < 4; ++r2) {
          float x = v[r2];
          v[r2] = 0.5f * x * (1.f + erff(x * 0.70710678118654752f));
        }
      }
      if (resid_mode == 1) {
        float4 rv = *(const float4*)(resid + (long)m * 256 + n);
        v[0] += rv.x; v[1] += rv.y; v[2] += rv.z; v[3] += rv.w;
      } else if (resid_mode == 2) {
        float4 rv = *(const float4*)(resid + orow * 256 + n);
        v[0] += rv.x; v[1] += rv.y; v[2] += rv.z; v[3] += rv.w;
      }
      if (out_mode == 2) {
        uint2 pk;
        pk.x = (u32)f2bs(v[0]) | ((u32)f2bs(v[1]) << 16);
        pk.y = (u32)f2bs(v[2]) | ((u32)f2bs(v[3]) << 16);
        *(uint2*)(Cb + (long)m * N + n) = pk;
      } else {
        float4 o4; o4.x = v[0]; o4.y = v[1]; o4.z = v[2]; o4.w = v[3];
        if (out_mode == 1) *(float4*)(Cf + orow * 256 + n) = o4;
        else               *(float4*)(Cf + (long)m * N + n) = o4;
      }
    }
  }
}

// ---------------------------------------------------------------------------
// Spatial 3x3 windowed attention on packed QKV [m][768] bf16. One thread per
// (pixel, head), head-fast. o over q in-place. (Q/K head-dim permutation is
// common to q and k -> dot products unchanged.)
// ---------------------------------------------------------------------------
__global__ __launch_bounds__(256)
void spatial_attn_kernel(ushort_t* __restrict__ qkv) {
  int gid = blockIdx.x * 256 + threadIdx.x;   // 262144
  int head = gid & 7, pixel = gid >> 3;
  int pix = pixel & 1023, bt = pixel >> 10;
  int y = pix >> 5, x = pix & 31;
  long rb = (long)bt << 10;
  const float scale = 0.17677669529663687f;   // 1/sqrt(32)

  float qf[32];
  long qoff = (long)pixel * 768 + head * 32;
  #pragma unroll
  for (int i = 0; i < 4; ++i) {
    bf16x8 t = *(const bf16x8*)(qkv + qoff + i * 8);
    #pragma unroll
    for (int e = 0; e < 8; ++e) qf[i * 8 + e] = bs2f((ushort_t)t[e]);
  }

  float s[9];
  bool val[9];
  #pragma unroll
  for (int n = 0; n < 9; ++n) {
    int yy = y + n / 3 - 1, xx = x + n % 3 - 1;
    bool ok = ((unsigned)yy < 32u) & ((unsigned)xx < 32u);
    val[n] = ok;
    float d = 0.f;
    if (ok) {
      long ko = (rb + (yy << 5) + xx) * 768 + 256 + head * 32;
      #pragma unroll
      for (int i = 0; i < 4; ++i) {
        bf16x8 t = *(const bf16x8*)(qkv + ko + i * 8);
        #pragma unroll
        for (int e = 0; e < 8; ++e) d += qf[i * 8 + e] * bs2f((ushort_t)t[e]);
      }
    }
    s[n] = d * scale;
  }
  float mx = -1e30f;
  #pragma unroll
  for (int n = 0; n < 9; ++n) if (val[n]) mx = fmaxf(mx, s[n]);
  float sum = 0.f;
  #pragma unroll
  for (int n = 0; n < 9; ++n) { s[n] = val[n] ? __expf(s[n] - mx) : 0.f; sum += s[n]; }
  float inv = 1.f / sum;

  float o[32];
  #pragma unroll
  for (int i = 0; i < 32; ++i) o[i] = 0.f;
  #pragma unroll
  for (int n = 0; n < 9; ++n) {
    if (val[n]) {
      int yy = y + n / 3 - 1, xx = x + n % 3 - 1;
      long vo = (rb + (yy << 5) + xx) * 768 + 512 + head * 32;
      #pragma unroll
      for (int i = 0; i < 4; ++i) {
        bf16x8 t = *(const bf16x8*)(qkv + vo + i * 8);
        #pragma unroll
        for (int e = 0; e < 8; ++e) o[i * 8 + e] += s[n] * bs2f((ushort_t)t[e]);
      }
    }
  }
  #pragma unroll
  for (int i = 0; i < 4; ++i) {
    bf16x8 t;
    #pragma unroll
    for (int e = 0; e < 8; ++e) t[e] = (short)f2bs(o[i * 8 + e] * inv);
    *(bf16x8*)(qkv + qoff + i * 8) = t;
  }
}

// ---------------------------------------------------------------------------
// Temporal attention (full 9x9; mask all-False). o over q in-place.
// ---------------------------------------------------------------------------
__global__ __launch_bounds__(256)
void temporal_attn_kernel(ushort_t* __restrict__ qkv) {
  int tid = threadIdx.x;
  int head = tid & 7, hwi = tid >> 3;
  int bi = blockIdx.x;                          // 1152 = 9 * 4 * 32
  int tq = bi >> 7;
  int rest = bi & 127;
  int b = rest >> 5, hwg = rest & 31;
  int hw = (hwg << 5) + hwi;
  long base = (long)(b * TQ_) * 1024 + hw;
  const float scale = 0.17677669529663687f;

  float qf[32];
  long qoff = (base + (long)tq * 1024) * 768 + head * 32;
  #pragma unroll
  for (int i = 0; i < 4; ++i) {
    bf16x8 t = *(const bf16x8*)(qkv + qoff + i * 8);
    #pragma unroll
    for (int e = 0; e < 8; ++e) qf[i * 8 + e] = bs2f((ushort_t)t[e]);
  }
  float s[9];
  #pragma unroll
  for (int tk = 0; tk < 9; ++tk) {
    long ko = (base + (long)tk * 1024) * 768 + 256 + head * 32;
    float d = 0.f;
    #pragma unroll
    for (int i = 0; i < 4; ++i) {
      bf16x8 t = *(const bf16x8*)(qkv + ko + i * 8);
      #pragma unroll
      for (int e = 0; e < 8; ++e) d += qf[i * 8 + e] * bs2f((ushort_t)t[e]);
    }
    s[tk] = d * scale;
  }
  float mx = s[0];
  #pragma unroll
  for (int tk = 1; tk < 9; ++tk) mx = fmaxf(mx, s[tk]);
  float sum = 0.f;
  #pragma unroll
  for (int tk = 0; tk < 9; ++tk) { s[tk] = __expf(s[tk] - mx); sum += s[tk]; }
  float inv = 1.f / sum;

  float o[32];
  #pragma unroll
  for (int i = 0; i < 32; ++i) o[i] = 0.f;
  #pragma unroll
  for (int tk = 0; tk < 9; ++tk) {
    long vo = (base + (long)tk * 1024) * 768 + 512 + head * 32;
    #pragma unroll
    for (int i = 0; i < 4; ++i) {
      bf16x8 t = *(const bf16x8*)(qkv + vo + i * 8);
      #pragma unroll
      for (int e = 0; e < 8; ++e) o[i * 8 + e] += s[tk] * bs2f((ushort_t)t[e]);
    }
  }
  #pragma unroll
  for (int i = 0; i < 4; ++i) {
    bf16x8 t;
    #pragma unroll
    for (int e = 0; e < 8; ++e) t[e] = (short)f2bs(o[i * 8 + e] * inv);
    *(bf16x8*)(qkv + qoff + i * 8) = t;
  }
}

// copy query frame 8 into x (f32); identical linear indices in both buffers
__global__ __launch_bounds__(256)
void copy_frame8_kernel(const float* __restrict__ qy, float* __restrict__ x) {
  long i = (long)blockIdx.x * 256 + threadIdx.x;
  int b = (int)(i >> 18);
  long rem = i & ((1L << 18) - 1);
  long gi = ((long)(b * TQ_ + 8) << 18) + rem;
  x[gi] = qy[gi];
}

// CLS frame mean over spatial: partial sums then broadcast (on f32 x)
__global__ __launch_bounds__(256)
void cls_sum_kernel(const float* __restrict__ x, float* __restrict__ partial) {
  int b = blockIdx.x >> 5, ch = blockIdx.x & 31;
  int d = threadIdx.x;
  long base = ((long)(b * TQ_) * 1024 + ch * 32) * 256 + d;
  float s = 0.f;
  for (int r = 0; r < 32; ++r) s += x[base + (long)r * 256];
  partial[(long)blockIdx.x * 256 + d] = s;
}

__global__ __launch_bounds__(256)
void cls_bcast_kernel(float* __restrict__ x, const float* __restrict__ partial) {
  int b = blockIdx.x >> 3, seg = blockIdx.x & 7;
  int d = threadIdx.x;
  float s = 0.f;
  for (int j = 0; j < 32; ++j) s += partial[(long)(b * 32 + j) * 256 + d];
  s *= (1.f / 1024.f);
  long base = ((long)(b * TQ_) * 1024 + seg * 128) * 256 + d;
  for (int r = 0; r < 128; ++r) x[base + (long)r * 256] = s;
}

// ---------------------------------------------------------------------------
extern "C" void kernel_launch(void* const* d_in, const int* in_sizes, int n_in,
                              void* d_out, int out_size, void* d_ws, size_t ws_size,
                              hipStream_t stream) {
  (void)in_sizes; (void)n_in; (void)out_size; (void)ws_size;
  const float* query = (const float*)d_in[0];
  const float* sln_g = (const float*)d_in[3];
  const float* sln_b = (const float*)d_in[4];
  const float* s_wq  = (const float*)d_in[5];
  const float* s_bq  = (const float*)d_in[6];
  const float* s_wk  = (const float*)d_in[7];
  const float* s_bk  = (const float*)d_in[8];
  const float* s_wv  = (const float*)d_in[9];
  const float* s_bv  = (const float*)d_in[10];
  const float* s_wo  = (const float*)d_in[11];
  const float* s_bo  = (const float*)d_in[12];
  const float* tln_g = (const float*)d_in[13];
  const float* tln_b = (const float*)d_in[14];
  const float* t_wq  = (const float*)d_in[15];
  const float* t_bq  = (const float*)d_in[16];
  const float* t_wk  = (const float*)d_in[17];
  const float* t_bk  = (const float*)d_in[18];
  const float* t_wv  = (const float*)d_in[19];
  const float* t_bv  = (const float*)d_in[20];
  const float* t_wo  = (const float*)d_in[21];
  const float* t_bo  = (const float*)d_in[22];
  const float* mln_g = (const float*)d_in[23];
  const float* mln_b = (const float*)d_in[24];
  const float* w1    = (const float*)d_in[25];
  const float* b1    = (const float*)d_in[26];
  const float* w2    = (const float*)d_in[27];
  const float* b2    = (const float*)d_in[28];
  float* out = (float*)d_out;

  // ---- workspace (~115.4 MB) ----
  const long RB = 36864L * 256;
  ushort_t* XA  = (ushort_t*)d_ws;          // RB bf16
  ushort_t* QKV = XA + RB;                  // 3*RB bf16, rows of 768
  float*    P4  = (float*)(QKV + 3 * RB);   // RB f32 (free during MLP)
  ushort_t* wt  = (ushort_t*)(P4 + RB);     // 2 MB packed weights
  float* bias2  = (float*)(wt + 1048576);   // 2x768 f32
  float* clsp   = bias2 + 1536;             // 128*256 f32
  // MLP hidden: 36864x1024 bf16 = 75.5 MB, spans QKV (56.6) + P4 (first half)
  ushort_t* hid = QKV;

  ushort_t* pk_sqkv = wt;                   // packed [768][256]
  ushort_t* pk_tqkv = wt + 196608;          // packed [768][256]
  ushort_t* pk_swo  = wt + 393216;          // packed [256][256]
  ushort_t* pk_two  = wt + 458752;          // packed [256][256]
  ushort_t* pk_w1   = wt + 524288;          // packed [1024][256]
  ushort_t* pk_w2   = wt + 786432;          // packed [256][1024]

  // ---- weight / bias prep (one pack dispatch) ----
  TPA tp;
  tp.s[0] = s_wq; tp.d[0] = pk_sqkv;          tp.K[0] = 256;  tp.N[0] = 256;  tp.pm[0] = 1;
  tp.s[1] = s_wk; tp.d[1] = pk_sqkv + 65536;  tp.K[1] = 256;  tp.N[1] = 256;  tp.pm[1] = 1;
  tp.s[2] = s_wv; tp.d[2] = pk_sqkv + 131072; tp.K[2] = 256;  tp.N[2] = 256;  tp.pm[2] = 0;
  tp.s[3] = t_wq; tp.d[3] = pk_tqkv;          tp.K[3] = 256;  tp.N[3] = 256;  tp.pm[3] = 1;
  tp.s[4] = t_wk; tp.d[4] = pk_tqkv + 65536;  tp.K[4] = 256;  tp.N[4] = 256;  tp.pm[4] = 1;
  tp.s[5] = t_wv; tp.d[5] = pk_tqkv + 131072; tp.K[5] = 256;  tp.N[5] = 256;  tp.pm[5] = 0;
  tp.s[6] = s_wo; tp.d[6] = pk_swo;           tp.K[6] = 256;  tp.N[6] = 256;  tp.pm[6] = 0;
  tp.s[7] = t_wo; tp.d[7] = pk_two;           tp.K[7] = 256;  tp.N[7] = 256;  tp.pm[7] = 0;
  tp.s[8] = w1;   tp.d[8] = pk_w1;            tp.K[8] = 256;  tp.N[8] = 1024; tp.pm[8] = 0;
  tp.s[9] = w2;   tp.d[9] = pk_w2;            tp.K[9] = 1024; tp.N[9] = 256;  tp.pm[9] = 0;
  pack_all_kernel<<<dim3(32, 32, 10), 256, 0, stream>>>(tp);
  BC6 bc;
  bc.b[0] = s_bq; bc.b[1] = s_bk; bc.b[2] = s_bv;
  bc.b[3] = t_bq; bc.b[4] = t_bk; bc.b[5] = t_bv;
  bias_concat_kernel<<<2, 768, 0, stream>>>(bc, bias2);

  // grid = (M/128)*(N/64) blocks, XCD-group-swizzled inside; NBq = N/256
  #define WGEMM(KV, Ap, ldav, Wp, bi, rs, CF, CB, M, N, rm, om, ac, rp)     \
    wgemm_kernel<KV><<<dim3(((M) / 128) * ((N) / 64)), 256, 0, stream>>>(   \
        Ap, ldav, Wp, bi, rs, CF, CB, N, (N) / 256, rm, om, ac, rp)

  // ---- spatial windowed attention (frames 0..7), M=32768 ----
  ln_norm_kernel<<<8192, 256, 0, stream>>>(query, 1, sln_g, sln_b, XA);
  WGEMM(256, XA, 256, pk_sqkv, bias2, nullptr, nullptr, QKV,
        32768, 768, 0, 2, 0, 0);
  spatial_attn_kernel<<<1024, 256, 0, stream>>>(QKV);
  WGEMM(256, QKV, 768, pk_swo, s_bo, query, P4, nullptr,
        32768, 256, 2, 1, 0, 0);
  copy_frame8_kernel<<<4096, 256, 0, stream>>>(query, P4);

  // ---- temporal RoPE attention, M=36864 ----
  ln_norm_kernel<<<9216, 256, 0, stream>>>(P4, 0, tln_g, tln_b, XA);
  WGEMM(256, XA, 256, pk_tqkv, bias2 + 768, nullptr, nullptr, QKV,
        36864, 768, 0, 2, 0, 1);
  temporal_attn_kernel<<<1152, 256, 0, stream>>>(QKV);
  WGEMM(256, QKV, 768, pk_two, t_bo, P4, out, nullptr,
        36864, 256, 1, 0, 0, 0);

  // ---- CLS frame spatial mean + broadcast (on out = x2) ----
  cls_sum_kernel<<<128, 256, 0, stream>>>(out, clsp);
  cls_bcast_kernel<<<32, 256, 0, stream>>>(out, clsp);

  // ---- MLP, full-M (hid spans QKV+P4) ----
  ln_norm_kernel<<<9216, 256, 0, stream>>>(out, 0, mln_g, mln_b, XA);
  WGEMM(256, XA, 256, pk_w1, b1, nullptr, nullptr, hid,
        36864, 1024, 0, 2, 1, 0);
  WGEMM(1024, hid, 1024, pk_w2, b2, out, out, nullptr,
        36864, 256, 1, 0, 0, 0);
  #undef WGEMM
}